// Round 6
// baseline (297.878 us; speedup 1.0000x reference)
//
#include <hip/hip_runtime.h>
#include <hip/hip_bf16.h>
#include <math.h>

typedef __hip_bfloat16 bf16;
typedef __attribute__((ext_vector_type(8))) short bf16x8;
typedef __attribute__((ext_vector_type(4))) short bf16x4;
typedef __attribute__((ext_vector_type(4))) float f32x4;

__device__ __forceinline__ float b2f(bf16 v) { return __bfloat162float(v); }
__device__ __forceinline__ bf16  f2b(float v) { return __float2bfloat16(v); }
__device__ __forceinline__ float s2f(short v) { return __uint_as_float(((unsigned)(unsigned short)v) << 16); }

// ---------------------------------------------------------------------------
// Input dtype detection: 1 = fp32 buffers, 0 = bf16 buffers.
// ---------------------------------------------------------------------------
__global__ void detect_dtype(const void* x, int* flag)
{
    __shared__ int cnt;
    if (threadIdx.x == 0) cnt = 0;
    __syncthreads();
    const unsigned* w = (const unsigned*)x;
    int sane = 0;
    for (int i = threadIdx.x; i < 2048; i += 256) {
        unsigned lo = (w[i] & 0xFFFFu) << 16;
        float v = __uint_as_float(lo);
        float a = fabsf(v);
        if (v == 0.f || (a > 1e-8f && a < 1e4f)) sane++;
    }
    atomicAdd(&cnt, sane);
    __syncthreads();
    if (threadIdx.x == 0) *flag = (cnt < 1640) ? 1 : 0;
}

// x convert, 4 elems/thread
__global__ void convert_x4(const void* __restrict__ src, bf16* __restrict__ dst,
                           const int* __restrict__ flag)
{
    int i = blockIdx.x * 256 + threadIdx.x;   // 1048576 quads
    bf16 tmp[4];
    if (*flag) {
        float4 v = ((const float4*)src)[i];
        tmp[0] = f2b(v.x); tmp[1] = f2b(v.y); tmp[2] = f2b(v.z); tmp[3] = f2b(v.w);
        *(bf16x4*)&dst[i * 4] = *(bf16x4*)tmp;
    } else {
        ((bf16x4*)dst)[i] = ((const bf16x4*)src)[i];
    }
}

// all small tensors in one launch, one block per tensor
struct PackArgs { const void* src[10]; bf16* dst[10]; int n[10]; };
__global__ void pack_small(PackArgs a, const int* __restrict__ flag)
{
    int bi = blockIdx.x;
    int n = a.n[bi];
    const void* s = a.src[bi];
    bf16* d = a.dst[bi];
    for (int i = threadIdx.x; i < n; i += 256)
        d[i] = (*flag) ? f2b(((const float*)s)[i]) : f2b(s2f(((const short*)s)[i]));
}

// six (K=256,N) weights -> WT[n*256+k], one launch
struct WTArgs { const void* src[6]; bf16* dst[6]; int N[6]; int blkoff[7]; };
__global__ void convert_wT_multi(WTArgs a, const int* __restrict__ flag)
{
    int blk = blockIdx.x;
    int ti = 0;
    while (blk >= a.blkoff[ti + 1]) ++ti;
    int o = (blk - a.blkoff[ti]) * 256 + threadIdx.x;
    int n = o >> 8, k = o & 255;
    int N = a.N[ti];
    float v = (*flag) ? ((const float*)a.src[ti])[k * N + n]
                      : s2f(((const short*)a.src[ti])[k * N + n]);
    a.dst[ti][o] = f2b(v);
}

// sr_w (256co, 256ci, 2, 2) -> WT[co*1024 + (e*256+ci)]
__global__ void convert_srwT(const void* __restrict__ src, bf16* __restrict__ dst,
                             const int* __restrict__ flag)
{
    int o = blockIdx.x * 256 + threadIdx.x;   // 262144
    int co = o >> 10, kg = o & 1023;
    int e = kg >> 8, ci = kg & 255;
    int si = co * 1024 + ci * 4 + e;
    float v = (*flag) ? ((const float*)src)[si] : s2f(((const short*)src)[si]);
    dst[o] = f2b(v);
}

// lepe_conv_w (256c,9) -> dwT[k*256+c]
__global__ void convert_dwT(const void* __restrict__ src, bf16* __restrict__ dst,
                            const int* __restrict__ flag)
{
    int o = blockIdx.x * 256 + threadIdx.x;   // 2304
    if (o >= 2304) return;
    int k = o >> 8, c = o & 255;
    float v = (*flag) ? ((const float*)src)[c * 9 + k] : s2f(((const short*)src)[c * 9 + k]);
    dst[o] = f2b(v);
}

// ---------------------------------------------------------------------------
// 128x128-tile MFMA GEMM for the fused QKV projection. M=16384, K=256.
// grid (128, 6). Wave (wr,wc) computes a 64x64 quadrant (4x4 16x16 frags).
// ---------------------------------------------------------------------------
__global__ __launch_bounds__(256) void gemm_qkv128(
    const bf16* __restrict__ A, const bf16* __restrict__ WT, const bf16* __restrict__ bias,
    bf16* __restrict__ Cl, bf16* __restrict__ Cq1, bf16* __restrict__ Cq2, bf16* __restrict__ Ckv2)
{
    __shared__ bf16 As[128][40];
    __shared__ bf16 Bs[128][40];
    int t = threadIdx.x;
    int m0 = blockIdx.x * 128, ybase = blockIdx.y * 128;
    int w = t >> 6, l = t & 63, lane16 = l & 15, quad = l >> 4;
    int wr = w >> 1, wc = w & 1;
    int sr = t >> 1, sc = (t & 1) * 16;
    f32x4 acc[4][4] = {};
    for (int k0 = 0; k0 < 256; k0 += 32) {
        *(bf16x8*)&As[sr][sc]     = *(const bf16x8*)&A[(size_t)(m0 + sr) * 256 + k0 + sc];
        *(bf16x8*)&As[sr][sc + 8] = *(const bf16x8*)&A[(size_t)(m0 + sr) * 256 + k0 + sc + 8];
        *(bf16x8*)&Bs[sr][sc]     = *(const bf16x8*)&WT[(size_t)(ybase + sr) * 256 + k0 + sc];
        *(bf16x8*)&Bs[sr][sc + 8] = *(const bf16x8*)&WT[(size_t)(ybase + sr) * 256 + k0 + sc + 8];
        __syncthreads();
        bf16x8 a[4], b[4];
        #pragma unroll
        for (int i = 0; i < 4; ++i) {
            a[i] = *(const bf16x8*)&As[wr * 64 + i * 16 + lane16][quad * 8];
            b[i] = *(const bf16x8*)&Bs[wc * 64 + i * 16 + lane16][quad * 8];
        }
        #pragma unroll
        for (int i = 0; i < 4; ++i)
            #pragma unroll
            for (int j = 0; j < 4; ++j)
                acc[i][j] = __builtin_amdgcn_mfma_f32_16x16x32_bf16(a[i], b[j], acc[i][j], 0, 0, 0);
        __syncthreads();
    }
    bf16* C; int N, cbase;
    if (ybase < 256)      { C = Cl;   N = 256; cbase = ybase; }
    else if (ybase < 384) { C = Cq1;  N = 128; cbase = ybase - 256; }
    else if (ybase < 512) { C = Cq2;  N = 128; cbase = ybase - 384; }
    else                  { C = Ckv2; N = 256; cbase = ybase - 512; }
    #pragma unroll
    for (int j = 0; j < 4; ++j) {
        int gcol = ybase + wc * 64 + j * 16 + lane16;
        float bv = b2f(bias[gcol]);
        int col = cbase + wc * 64 + j * 16 + lane16;
        #pragma unroll
        for (int i = 0; i < 4; ++i)
            #pragma unroll
            for (int r = 0; r < 4; ++r) {
                int row = m0 + wr * 64 + i * 16 + quad * 4 + r;
                C[(size_t)row * N + col] = f2b(acc[i][j][r] + bv);
            }
    }
}

// proj GEMM, 128x128 tile: out = 2*((attn+lepe) @ proj_w + bias). grid (128,2).
__global__ __launch_bounds__(256) void gemm_proj128(
    const bf16* __restrict__ A, const bf16* __restrict__ A2,
    const bf16* __restrict__ WT, const bf16* __restrict__ bias,
    void* __restrict__ dout, const int* __restrict__ flag)
{
    __shared__ bf16 As[128][40];
    __shared__ bf16 Bs[128][40];
    int t = threadIdx.x;
    int m0 = blockIdx.x * 128, n0 = blockIdx.y * 128;
    int w = t >> 6, l = t & 63, lane16 = l & 15, quad = l >> 4;
    int wr = w >> 1, wc = w & 1;
    int sr = t >> 1, sc = (t & 1) * 16;
    f32x4 acc[4][4] = {};
    for (int k0 = 0; k0 < 256; k0 += 32) {
        #pragma unroll
        for (int hh = 0; hh < 2; ++hh) {
            bf16x8 va = *(const bf16x8*)&A[(size_t)(m0 + sr) * 256 + k0 + sc + hh * 8];
            bf16x8 vb = *(const bf16x8*)&A2[(size_t)(m0 + sr) * 256 + k0 + sc + hh * 8];
            bf16 tmp[8];
            #pragma unroll
            for (int q = 0; q < 8; ++q) tmp[q] = f2b(s2f(va[q]) + s2f(vb[q]));
            *(bf16x8*)&As[sr][sc + hh * 8] = *(bf16x8*)tmp;
        }
        *(bf16x8*)&Bs[sr][sc]     = *(const bf16x8*)&WT[(size_t)(n0 + sr) * 256 + k0 + sc];
        *(bf16x8*)&Bs[sr][sc + 8] = *(const bf16x8*)&WT[(size_t)(n0 + sr) * 256 + k0 + sc + 8];
        __syncthreads();
        bf16x8 a[4], b[4];
        #pragma unroll
        for (int i = 0; i < 4; ++i) {
            a[i] = *(const bf16x8*)&As[wr * 64 + i * 16 + lane16][quad * 8];
            b[i] = *(const bf16x8*)&Bs[wc * 64 + i * 16 + lane16][quad * 8];
        }
        #pragma unroll
        for (int i = 0; i < 4; ++i)
            #pragma unroll
            for (int j = 0; j < 4; ++j)
                acc[i][j] = __builtin_amdgcn_mfma_f32_16x16x32_bf16(a[i], b[j], acc[i][j], 0, 0, 0);
        __syncthreads();
    }
    #pragma unroll
    for (int j = 0; j < 4; ++j) {
        int col = n0 + wc * 64 + j * 16 + lane16;
        float bv = b2f(bias[col]);
        #pragma unroll
        for (int i = 0; i < 4; ++i)
            #pragma unroll
            for (int r = 0; r < 4; ++r) {
                int row = m0 + wr * 64 + i * 16 + quad * 4 + r;
                float rv = (acc[i][j][r] + bv) * 2.f;
                size_t o = (size_t)row * 256 + col;
                if (*flag) ((float*)dout)[o] = rv;
                else       ((bf16*)dout)[o] = f2b(rv);
            }
    }
}

// sr conv as MFMA GEMM with gathered A rows. M=4096, N=256, K=1024. (r4-verified)
__global__ __launch_bounds__(256) void gemm_sr_mfma(
    const bf16* __restrict__ x, const bf16* __restrict__ WT,
    const bf16* __restrict__ bias, bf16* __restrict__ C)
{
    __shared__ bf16 As[64][40];
    __shared__ bf16 Bs[64][40];
    int t = threadIdx.x;
    int m0 = blockIdx.x * 64, n0 = blockIdx.y * 64;
    int w = t >> 6, l = t & 63, lane16 = l & 15, quad = l >> 4;
    int sr = t >> 2, sc = (t & 3) * 8;
    int brow = m0 + sr;
    int b = brow >> 10, p = brow & 1023;
    int pi = p >> 5, pj = p & 31;
    f32x4 acc[4] = {};
    for (int k0 = 0; k0 < 1024; k0 += 32) {
        int kg = k0 + sc;
        int e = kg >> 8, ci = kg & 255;
        int di = e >> 1, dj = e & 1;
        int n = (2 * pi + di) * 64 + 2 * pj + dj;
        *(bf16x8*)&As[sr][sc] = *(const bf16x8*)&x[(size_t)((b << 12) + n) * 256 + ci];
        *(bf16x8*)&Bs[sr][sc] = *(const bf16x8*)&WT[(size_t)(n0 + sr) * 1024 + kg];
        __syncthreads();
        bf16x8 a = *(const bf16x8*)&As[w * 16 + lane16][quad * 8];
        #pragma unroll
        for (int ct = 0; ct < 4; ++ct) {
            bf16x8 bb = *(const bf16x8*)&Bs[ct * 16 + lane16][quad * 8];
            acc[ct] = __builtin_amdgcn_mfma_f32_16x16x32_bf16(a, bb, acc[ct], 0, 0, 0);
        }
        __syncthreads();
    }
    #pragma unroll
    for (int ct = 0; ct < 4; ++ct) {
        int col = n0 + ct * 16 + lane16;
        float bv = b2f(bias[col]);
        #pragma unroll
        for (int r = 0; r < 4; ++r) {
            int row = m0 + w * 16 + quad * 4 + r;
            C[(size_t)row * 256 + col] = f2b(acc[ct][r] + bv);
        }
    }
}

// kv1 GEMM: xs[4096,256] @ kv1_w + b; K-half -> k1[b,key,h,ch] (stride 128),
// V-half transposed -> v1T[b,h,ch,key]. (r5-verified)
__global__ __launch_bounds__(256) void gemm_kv1(
    const bf16* __restrict__ A, const bf16* __restrict__ WT, const bf16* __restrict__ bias,
    bf16* __restrict__ k1, bf16* __restrict__ v1T)
{
    __shared__ bf16 As[64][40];
    __shared__ bf16 Bs[64][40];
    int t = threadIdx.x;
    int m0 = blockIdx.x * 64, n0 = blockIdx.y * 64;
    int w = t >> 6, l = t & 63, lane16 = l & 15, quad = l >> 4;
    int sr = t >> 2, sc = (t & 3) * 8;
    f32x4 acc[4] = {};
    for (int k0 = 0; k0 < 256; k0 += 32) {
        *(bf16x8*)&As[sr][sc] = *(const bf16x8*)&A[(size_t)(m0 + sr) * 256 + k0 + sc];
        *(bf16x8*)&Bs[sr][sc] = *(const bf16x8*)&WT[(size_t)(n0 + sr) * 256 + k0 + sc];
        __syncthreads();
        bf16x8 a = *(const bf16x8*)&As[w * 16 + lane16][quad * 8];
        #pragma unroll
        for (int ct = 0; ct < 4; ++ct) {
            bf16x8 b = *(const bf16x8*)&Bs[ct * 16 + lane16][quad * 8];
            acc[ct] = __builtin_amdgcn_mfma_f32_16x16x32_bf16(a, b, acc[ct], 0, 0, 0);
        }
        __syncthreads();
    }
    #pragma unroll
    for (int ct = 0; ct < 4; ++ct) {
        int col = n0 + ct * 16 + lane16;
        float bv = b2f(bias[col]);
        #pragma unroll
        for (int r = 0; r < 4; ++r) {
            int row = m0 + w * 16 + quad * 4 + r;
            float val = acc[ct][r] + bv;
            int bb = row >> 10, key = row & 1023;
            if (col < 128) {
                k1[(size_t)row * 128 + col] = f2b(val);
            } else {
                int h = (col - 128) >> 5, ch = (col - 128) & 31;
                v1T[(size_t)((bb * 4 + h) * 32 + ch) * 1024 + key] = f2b(val);
            }
        }
    }
}

// ---------------------------------------------------------------------------
// depthwise 3x3, vectorized: one thread per 8 channels.
// ---------------------------------------------------------------------------
__global__ __launch_bounds__(256) void dwconv3v(
    const bf16* __restrict__ lin, const bf16* __restrict__ dwT,
    const bf16* __restrict__ bias, bf16* __restrict__ out)
{
    int tid = blockIdx.x * 256 + threadIdx.x;   // 524288
    int c0 = (tid & 31) * 8;
    int n = (tid >> 5) & 4095;
    int b = tid >> 17;
    int i = n >> 6, j = n & 63;
    float acc[8];
    bf16x8 bv = *(const bf16x8*)&bias[c0];
    #pragma unroll
    for (int q = 0; q < 8; ++q) acc[q] = s2f(bv[q]);
    #pragma unroll
    for (int di = 0; di < 3; ++di) {
        int ii = i + di - 1;
        if (ii < 0 || ii > 63) continue;
        #pragma unroll
        for (int dj = 0; dj < 3; ++dj) {
            int jj = j + dj - 1;
            if (jj < 0 || jj > 63) continue;
            bf16x8 xv = *(const bf16x8*)&lin[(size_t)((b << 12) + ii * 64 + jj) * 256 + c0];
            bf16x8 wv = *(const bf16x8*)&dwT[(di * 3 + dj) * 256 + c0];
            #pragma unroll
            for (int q = 0; q < 8; ++q) acc[q] += s2f(xv[q]) * s2f(wv[q]);
        }
    }
    bf16 ov[8];
    #pragma unroll
    for (int q = 0; q < 8; ++q) ov[q] = f2b(acc[q]);
    *(bf16x8*)&out[(size_t)((b << 12) + n) * 256 + c0] = *(bf16x8*)ov;
}

// ---------------------------------------------------------------------------
// layernorm+gelu, one wave per row (4 ch/lane).
// ---------------------------------------------------------------------------
__global__ __launch_bounds__(256) void ln_gelu_w(
    const bf16* __restrict__ xin, const bf16* __restrict__ nw,
    const bf16* __restrict__ nb, bf16* __restrict__ xout)
{
    int w = threadIdx.x >> 6, lane = threadIdx.x & 63;
    int r = blockIdx.x * 4 + w;
    bf16x4 xv = *(const bf16x4*)&xin[(size_t)r * 256 + lane * 4];
    float v[4];
    #pragma unroll
    for (int j = 0; j < 4; ++j) v[j] = s2f(xv[j]);
    float s = v[0] + v[1] + v[2] + v[3];
    #pragma unroll
    for (int o = 1; o <= 32; o <<= 1) s += __shfl_xor(s, o);
    float mean = s * (1.f / 256.f);
    float ss = 0.f;
    #pragma unroll
    for (int j = 0; j < 4; ++j) { float d = v[j] - mean; ss += d * d; }
    #pragma unroll
    for (int o = 1; o <= 32; o <<= 1) ss += __shfl_xor(ss, o);
    float inv = rsqrtf(ss * (1.f / 256.f) + 1e-5f);
    bf16x4 wv = *(const bf16x4*)&nw[lane * 4];
    bf16x4 bv = *(const bf16x4*)&nb[lane * 4];
    bf16 ov[4];
    #pragma unroll
    for (int j = 0; j < 4; ++j) {
        float y = (v[j] - mean) * inv * s2f(wv[j]) + s2f(bv[j]);
        ov[j] = f2b(0.5f * y * (1.f + erff(y * 0.70710678118654752f)));
    }
    *(bf16x4*)&xout[(size_t)r * 256 + lane * 4] = *(bf16x4*)ov;
}

// ---------------------------------------------------------------------------
// Branch-1 attention, single-sweep S^T formulation, barrier-free main loops.
//  - S^T = mfma(Kfrag, Qfrag): lane holds 4 k-consecutive scores -> packed b64
//    write into wave-private PTT; P^T frag for PV read back as b128.
//  - PV: O^T = V^T @ P^T with unnormalized P; l accumulated per lane
//    (q = lane16); O scaled by 1/l at the end.
//  - K/V frags loaded directly from global (L2-hot), no LDS staging.
//  - Loop 2 (g only): S orientation = mfma(Qfrag, Kfrag) (r5-verified map),
//    normalized column sums via 2 shuffles + LDS atomic.
// Block 256 thr (4 indep waves, 16 q each), grid 1024 = b*h*qc.
// ---------------------------------------------------------------------------
__global__ __launch_bounds__(256) void attn1_mfma3(
    const bf16* __restrict__ q1, const bf16* __restrict__ k1,
    const bf16* __restrict__ v1T, bf16* __restrict__ attn_out, float* __restrict__ g)
{
    __shared__ bf16 PTT[4][16][72];   // per-wave P^T strip: [q][k]
    __shared__ float gp[1024];

    int t = threadIdx.x;
    int blk = blockIdx.x;
    int qc = blk & 63, h = (blk >> 6) & 3, b = blk >> 8;
    int n0 = qc * 64;
    int w = t >> 6, l = t & 63, lane16 = l & 15, quad = l >> 4;
    const float scale = 0.17677669529663687f;   // 1/sqrt(32)

    const bf16* Kbase = k1 + (size_t)b * 1024 * 128 + 32 * h;
    const bf16* Vbase = v1T + (size_t)((b * 4 + h) * 32) * 1024;
    bf16x8 qa = *(const bf16x8*)&q1[(size_t)(b * 4096 + n0 + 16 * w + lane16) * 128 + 32 * h + quad * 8];

    for (int i = t; i < 1024; i += 256) gp[i] = 0.f;
    __syncthreads();

    bf16* ptt = &PTT[w][0][0];
    float lacc = 0.f;
    f32x4 oT0 = {}, oT1 = {};

    // ---- sweep 1: unnormalized PV + l ----
    for (int kt = 0; kt < 16; ++kt) {
        bf16x8 kf[4];
        #pragma unroll
        for (int st = 0; st < 4; ++st)
            kf[st] = *(const bf16x8*)&Kbase[(size_t)(kt * 64 + st * 16 + lane16) * 128 + quad * 8];
        bf16x8 vf[2][2];
        #pragma unroll
        for (int ct = 0; ct < 2; ++ct)
            #pragma unroll
            for (int kh = 0; kh < 2; ++kh)
                vf[ct][kh] = *(const bf16x8*)&Vbase[(size_t)(ct * 16 + lane16) * 1024 + kt * 64 + kh * 32 + quad * 8];
        #pragma unroll
        for (int st = 0; st < 4; ++st) {
            f32x4 z = {0.f, 0.f, 0.f, 0.f};
            f32x4 sT = __builtin_amdgcn_mfma_f32_16x16x32_bf16(kf[st], qa, z, 0, 0, 0);
            bf16 pk[4];
            #pragma unroll
            for (int r = 0; r < 4; ++r) {
                float p = __expf(sT[r] * scale);
                lacc += p;
                pk[r] = f2b(p);
            }
            *(bf16x4*)&ptt[lane16 * 72 + st * 16 + quad * 4] = *(bf16x4*)pk;
        }
        #pragma unroll
        for (int kh = 0; kh < 2; ++kh) {
            bf16x8 pf = *(const bf16x8*)&ptt[lane16 * 72 + kh * 32 + quad * 8];
            oT0 = __builtin_amdgcn_mfma_f32_16x16x32_bf16(vf[0][kh], pf, oT0, 0, 0, 0);
            oT1 = __builtin_amdgcn_mfma_f32_16x16x32_bf16(vf[1][kh], pf, oT1, 0, 0, 0);
        }
    }
    lacc += __shfl_xor(lacc, 16);
    lacc += __shfl_xor(lacc, 32);
    float rl = 1.f / lacc;                 // 1/l for q = lane16
    float rlq[4];
    #pragma unroll
    for (int r = 0; r < 4; ++r) rlq[r] = __shfl(rl, quad * 4 + r);

    // ---- sweep 2: g column sums (normalized) ----
    for (int kt = 0; kt < 16; ++kt) {
        #pragma unroll
        for (int st = 0; st < 4; ++st) {
            bf16x8 kf = *(const bf16x8*)&Kbase[(size_t)(kt * 64 + st * 16 + lane16) * 128 + quad * 8];
            f32x4 z = {0.f, 0.f, 0.f, 0.f};
            f32x4 s = __builtin_amdgcn_mfma_f32_16x16x32_bf16(qa, kf, z, 0, 0, 0);
            float cs = 0.f;
            #pragma unroll
            for (int r = 0; r < 4; ++r) cs += __expf(s[r] * scale) * rlq[r];
            cs += __shfl_xor(cs, 16);
            cs += __shfl_xor(cs, 32);
            if (quad == 0) atomicAdd(&gp[kt * 64 + st * 16 + lane16], cs);
        }
    }

    // ---- store O (normalize by 1/l) ----
    #pragma unroll
    for (int ct = 0; ct < 2; ++ct) {
        f32x4 o = ct ? oT1 : oT0;
        bf16 ov[4];
        #pragma unroll
        for (int r = 0; r < 4; ++r) ov[r] = f2b(o[r] * rl);
        *(bf16x4*)&attn_out[(size_t)(b * 4096 + n0 + 16 * w + lane16) * 256 + 32 * h + ct * 16 + quad * 4] = *(bf16x4*)ov;
    }
    __syncthreads();
    for (int i = t; i < 1024; i += 256)
        atomicAdd(&g[(b << 10) + i], gp[i] * (1.f / 16384.f));
}

// ---------------------------------------------------------------------------
// Branch-2 windowed attention, vectorized loads (r5-verified).
// ---------------------------------------------------------------------------
__global__ __launch_bounds__(64) void attn2_vec(
    const bf16* __restrict__ q2, const bf16* __restrict__ kv2,
    bf16* __restrict__ attn_out, float* __restrict__ lm)
{
    __shared__ float P2[64][17];
    int t = threadIdx.x;
    int blk = blockIdx.x;
    int b = blk >> 8, win = blk & 255;
    int wi = win >> 4, wj = win & 15;
    int h = t >> 4, qi = t & 15;
    int nq = (wi * 4 + (qi >> 2)) * 64 + wj * 4 + (qi & 3);

    float qv[32];
    {
        const bf16* qp = q2 + (size_t)(b * 4096 + nq) * 128 + h * 32;
        #pragma unroll
        for (int g8 = 0; g8 < 4; ++g8) {
            bf16x8 v = *(const bf16x8*)&qp[g8 * 8];
            #pragma unroll
            for (int j = 0; j < 8; ++j) qv[g8 * 8 + j] = s2f(v[j]) * 0.17677669529663687f;
        }
    }
    float s[16];
    float mx = -1e30f;
    #pragma unroll
    for (int k = 0; k < 16; ++k) {
        int nk = (wi * 4 + (k >> 2)) * 64 + wj * 4 + (k & 3);
        const bf16* kp = kv2 + (size_t)(b * 4096 + nk) * 256 + h * 32;
        float ss = 0.f;
        #pragma unroll
        for (int g8 = 0; g8 < 4; ++g8) {
            bf16x8 v = *(const bf16x8*)&kp[g8 * 8];
            #pragma unroll
            for (int j = 0; j < 8; ++j) ss += qv[g8 * 8 + j] * s2f(v[j]);
        }
        s[k] = ss;
        mx = fmaxf(mx, ss);
    }
    float lsum = 0.f;
    #pragma unroll
    for (int k = 0; k < 16; ++k) { s[k] = __expf(s[k] - mx); lsum += s[k]; }
    float rl = 1.f / lsum;
    #pragma unroll
    for (int k = 0; k < 16; ++k) s[k] *= rl;

    float o[32];
    #pragma unroll
    for (int d = 0; d < 32; ++d) o[d] = 0.f;
    #pragma unroll
    for (int k = 0; k < 16; ++k) {
        int nk = (wi * 4 + (k >> 2)) * 64 + wj * 4 + (k & 3);
        const bf16* vp = kv2 + (size_t)(b * 4096 + nk) * 256 + 128 + h * 32;
        float p = s[k];
        #pragma unroll
        for (int g8 = 0; g8 < 4; ++g8) {
            bf16x8 v = *(const bf16x8*)&vp[g8 * 8];
            #pragma unroll
            for (int j = 0; j < 8; ++j) o[g8 * 8 + j] += p * s2f(v[j]);
        }
    }
    {
        bf16* op = attn_out + (size_t)(b * 4096 + nq) * 256 + 128 + h * 32;
        #pragma unroll
        for (int g8 = 0; g8 < 4; ++g8) {
            bf16 ov[8];
            #pragma unroll
            for (int j = 0; j < 8; ++j) ov[j] = f2b(o[g8 * 8 + j]);
            *(bf16x8*)&op[g8 * 8] = *(bf16x8*)ov;
        }
    }

    #pragma unroll
    for (int k = 0; k < 16; ++k) P2[t][k] = s[k];
    __syncthreads();
    if (t < 16) {
        float cs = 0.f;
        for (int qq = 0; qq < 64; ++qq) cs += P2[qq][t];
        int nk = (wi * 4 + (t >> 2)) * 64 + wj * 4 + (t & 3);
        lm[(b << 12) + nk] = cs * (1.f / 64.f);
    }
}

// ---------------------------------------------------------------------------
__global__ void mask_combine(const float* __restrict__ lm, const float* __restrict__ g,
                             void* __restrict__ dout, const int* __restrict__ flag)
{
    int tid = blockIdx.x * 256 + threadIdx.x;   // 16384
    int b = tid >> 12, n = tid & 4095;
    int i = n >> 6, j = n & 63;
    float v = lm[tid] + g[(b << 10) + (i >> 1) * 32 + (j >> 1)];
    size_t o1 = (size_t)4194304 + (b << 12) + i * 64 + j;
    size_t o2 = (size_t)4194304 + 16384 + (b << 12) + j * 64 + i;
    if (*flag) { ((float*)dout)[o1] = v; ((float*)dout)[o2] = v; }
    else       { ((bf16*)dout)[o1] = f2b(v); ((bf16*)dout)[o2] = f2b(v); }
}

// ---------------------------------------------------------------------------
extern "C" void kernel_launch(void* const* d_in, const int* in_sizes, int n_in,
                              void* d_out, int out_size, void* d_ws, size_t ws_size,
                              hipStream_t stream)
{
    char* ws = (char*)d_ws;
    size_t off = 0;
    auto alloc = [&](size_t bytes) {
        void* p = ws + off;
        off += (bytes + 255) & ~(size_t)255;
        return p;
    };
    bf16* cx       = (bf16*)alloc((size_t)4194304 * 2);
    bf16* lepe_lin = (bf16*)alloc((size_t)4194304 * 2);   // reused as attn_out
    bf16* attn_out = lepe_lin;
    bf16* lepe     = (bf16*)alloc((size_t)4194304 * 2);
    bf16* q1buf    = (bf16*)alloc((size_t)2097152 * 2);
    bf16* q2buf    = (bf16*)alloc((size_t)2097152 * 2);
    bf16* kv2buf   = (bf16*)alloc((size_t)4194304 * 2);
    bf16* xs_pre   = (bf16*)alloc((size_t)1048576 * 2);   // later reused: k1 + v1T
    bf16* k1buf    = xs_pre;                               // 524288 elems
    bf16* v1Tbuf   = xs_pre + 524288;                      // 524288 elems
    bf16* xs       = (bf16*)alloc((size_t)1048576 * 2);
    bf16* wTqkv    = (bf16*)alloc((size_t)196608 * 2);     // 768 x 256
    bf16* kv1_wT   = (bf16*)alloc(65536 * 2);
    bf16* proj_wT  = (bf16*)alloc(65536 * 2);
    bf16* sr_wT    = (bf16*)alloc(262144 * 2);
    bf16* dwT      = (bf16*)alloc(2304 * 2);
    bf16* bcat     = (bf16*)alloc(768 * 2);
    bf16* ckv1b    = (bf16*)alloc(256 * 2);
    bf16* csrb     = (bf16*)alloc(256 * 2);
    bf16* cnw      = (bf16*)alloc(256 * 2);
    bf16* cnb      = (bf16*)alloc(256 * 2);
    bf16* cpb      = (bf16*)alloc(256 * 2);
    bf16* clcb     = (bf16*)alloc(256 * 2);
    float* gbuf    = (float*)alloc(4096 * 4);
    float* lmbuf   = (float*)alloc(16384 * 4);
    int*   flag    = (int*)alloc(256);

    detect_dtype<<<1, 256, 0, stream>>>(d_in[0], flag);

    convert_x4<<<4096, 256, 0, stream>>>(d_in[0], cx, flag);

    PackArgs pa;
    pa.src[0] = d_in[10]; pa.dst[0] = bcat;       pa.n[0] = 256;  // lepe_b
    pa.src[1] = d_in[2];  pa.dst[1] = bcat + 256; pa.n[1] = 128;  // q1_b
    pa.src[2] = d_in[6];  pa.dst[2] = bcat + 384; pa.n[2] = 128;  // q2_b
    pa.src[3] = d_in[8];  pa.dst[3] = bcat + 512; pa.n[3] = 256;  // kv2_b
    pa.src[4] = d_in[4];  pa.dst[4] = ckv1b;      pa.n[4] = 256;
    pa.src[5] = d_in[14]; pa.dst[5] = csrb;       pa.n[5] = 256;
    pa.src[6] = d_in[15]; pa.dst[6] = cnw;        pa.n[6] = 256;
    pa.src[7] = d_in[16]; pa.dst[7] = cnb;        pa.n[7] = 256;
    pa.src[8] = d_in[18]; pa.dst[8] = cpb;        pa.n[8] = 256;
    pa.src[9] = d_in[12]; pa.dst[9] = clcb;       pa.n[9] = 256;
    pack_small<<<10, 256, 0, stream>>>(pa, flag);

    WTArgs wa;
    wa.src[0] = d_in[9];  wa.dst[0] = wTqkv;             wa.N[0] = 256;
    wa.src[1] = d_in[1];  wa.dst[1] = wTqkv + 256 * 256; wa.N[1] = 128;
    wa.src[2] = d_in[5];  wa.dst[2] = wTqkv + 384 * 256; wa.N[2] = 128;
    wa.src[3] = d_in[7];  wa.dst[3] = wTqkv + 512 * 256; wa.N[3] = 256;
    wa.src[4] = d_in[3];  wa.dst[4] = kv1_wT;            wa.N[4] = 256;
    wa.src[5] = d_in[17]; wa.dst[5] = proj_wT;           wa.N[5] = 256;
    int bo[7] = {0, 256, 384, 512, 768, 1024, 1280};
    for (int i = 0; i < 7; ++i) wa.blkoff[i] = bo[i];
    convert_wT_multi<<<1280, 256, 0, stream>>>(wa, flag);

    convert_srwT<<<1024, 256, 0, stream>>>(d_in[13], sr_wT, flag);
    convert_dwT<<<9, 256, 0, stream>>>(d_in[11], dwT, flag);

    hipMemsetAsync(gbuf, 0, 4096 * 4, stream);

    // fused x-projections (128x128 tile)
    gemm_qkv128<<<dim3(128, 6), 256, 0, stream>>>(cx, wTqkv, bcat, lepe_lin, q1buf, q2buf, kv2buf);
    // spatial reduction branch
    gemm_sr_mfma<<<dim3(64, 4), 256, 0, stream>>>(cx, sr_wT, csrb, xs_pre);
    ln_gelu_w<<<1024, 256, 0, stream>>>(xs_pre, cnw, cnb, xs);
    gemm_kv1<<<dim3(64, 4), 256, 0, stream>>>(xs, kv1_wT, ckv1b, k1buf, v1Tbuf);
    // lepe (consumes lepe_lin; must precede attn kernels which reuse that slot)
    dwconv3v<<<2048, 256, 0, stream>>>(lepe_lin, dwT, clcb, lepe);
    // attentions
    attn1_mfma3<<<1024, 256, 0, stream>>>(q1buf, k1buf, v1Tbuf, attn_out, gbuf);
    attn2_vec<<<1024, 64, 0, stream>>>(q2buf, kv2buf, attn_out, lmbuf);
    // projection epilogue (128x128 tile)
    gemm_proj128<<<dim3(128, 2), 256, 0, stream>>>(attn_out, lepe, proj_wT, cpb, d_out, flag);
    // masks
    mask_combine<<<64, 256, 0, stream>>>(lmbuf, gbuf, d_out, flag);
}

// Round 7
// 268.285 us; speedup vs baseline: 1.1103x; 1.1103x over previous
//
#include <hip/hip_runtime.h>
#include <hip/hip_bf16.h>
#include <math.h>

typedef __hip_bfloat16 bf16;
typedef __attribute__((ext_vector_type(8))) short bf16x8;
typedef __attribute__((ext_vector_type(4))) short bf16x4;
typedef __attribute__((ext_vector_type(4))) float f32x4;

__device__ __forceinline__ float b2f(bf16 v) { return __bfloat162float(v); }
__device__ __forceinline__ bf16  f2b(float v) { return __float2bfloat16(v); }
__device__ __forceinline__ float s2f(short v) { return __uint_as_float(((unsigned)(unsigned short)v) << 16); }

// ---------------------------------------------------------------------------
// Input dtype detection: 1 = fp32 buffers, 0 = bf16 buffers.
// ---------------------------------------------------------------------------
__global__ void detect_dtype(const void* x, int* flag)
{
    __shared__ int cnt;
    if (threadIdx.x == 0) cnt = 0;
    __syncthreads();
    const unsigned* w = (const unsigned*)x;
    int sane = 0;
    for (int i = threadIdx.x; i < 2048; i += 256) {
        unsigned lo = (w[i] & 0xFFFFu) << 16;
        float v = __uint_as_float(lo);
        float a = fabsf(v);
        if (v == 0.f || (a > 1e-8f && a < 1e4f)) sane++;
    }
    atomicAdd(&cnt, sane);
    __syncthreads();
    if (threadIdx.x == 0) *flag = (cnt < 1640) ? 1 : 0;
}

// x convert, 4 elems/thread
__global__ void convert_x4(const void* __restrict__ src, bf16* __restrict__ dst,
                           const int* __restrict__ flag)
{
    int i = blockIdx.x * 256 + threadIdx.x;   // 1048576 quads
    bf16 tmp[4];
    if (*flag) {
        float4 v = ((const float4*)src)[i];
        tmp[0] = f2b(v.x); tmp[1] = f2b(v.y); tmp[2] = f2b(v.z); tmp[3] = f2b(v.w);
        *(bf16x4*)&dst[i * 4] = *(bf16x4*)tmp;
    } else {
        ((bf16x4*)dst)[i] = ((const bf16x4*)src)[i];
    }
}

// all small tensors in one launch, one block per tensor
struct PackArgs { const void* src[10]; bf16* dst[10]; int n[10]; };
__global__ void pack_small(PackArgs a, const int* __restrict__ flag)
{
    int bi = blockIdx.x;
    int n = a.n[bi];
    const void* s = a.src[bi];
    bf16* d = a.dst[bi];
    for (int i = threadIdx.x; i < n; i += 256)
        d[i] = (*flag) ? f2b(((const float*)s)[i]) : f2b(s2f(((const short*)s)[i]));
}

// six (K=256,N) weights -> WT[n*256+k], one launch
struct WTArgs { const void* src[6]; bf16* dst[6]; int N[6]; int blkoff[7]; };
__global__ void convert_wT_multi(WTArgs a, const int* __restrict__ flag)
{
    int blk = blockIdx.x;
    int ti = 0;
    while (blk >= a.blkoff[ti + 1]) ++ti;
    int o = (blk - a.blkoff[ti]) * 256 + threadIdx.x;
    int n = o >> 8, k = o & 255;
    int N = a.N[ti];
    float v = (*flag) ? ((const float*)a.src[ti])[k * N + n]
                      : s2f(((const short*)a.src[ti])[k * N + n]);
    a.dst[ti][o] = f2b(v);
}

// sr_w (256co, 256ci, 2, 2) -> WT[co*1024 + (e*256+ci)]
__global__ void convert_srwT(const void* __restrict__ src, bf16* __restrict__ dst,
                             const int* __restrict__ flag)
{
    int o = blockIdx.x * 256 + threadIdx.x;   // 262144
    int co = o >> 10, kg = o & 1023;
    int e = kg >> 8, ci = kg & 255;
    int si = co * 1024 + ci * 4 + e;
    float v = (*flag) ? ((const float*)src)[si] : s2f(((const short*)src)[si]);
    dst[o] = f2b(v);
}

// lepe_conv_w (256c,9) -> dwT[k*256+c]
__global__ void convert_dwT(const void* __restrict__ src, bf16* __restrict__ dst,
                            const int* __restrict__ flag)
{
    int o = blockIdx.x * 256 + threadIdx.x;   // 2304
    if (o >= 2304) return;
    int k = o >> 8, c = o & 255;
    float v = (*flag) ? ((const float*)src)[c * 9 + k] : s2f(((const short*)src)[c * 9 + k]);
    dst[o] = f2b(v);
}

// ---------------------------------------------------------------------------
// 128x128-tile MFMA GEMM for the fused QKV projection. M=16384, K=256.
// ---------------------------------------------------------------------------
__global__ __launch_bounds__(256) void gemm_qkv128(
    const bf16* __restrict__ A, const bf16* __restrict__ WT, const bf16* __restrict__ bias,
    bf16* __restrict__ Cl, bf16* __restrict__ Cq1, bf16* __restrict__ Cq2, bf16* __restrict__ Ckv2)
{
    __shared__ bf16 As[128][40];
    __shared__ bf16 Bs[128][40];
    int t = threadIdx.x;
    int m0 = blockIdx.x * 128, ybase = blockIdx.y * 128;
    int w = t >> 6, l = t & 63, lane16 = l & 15, quad = l >> 4;
    int wr = w >> 1, wc = w & 1;
    int sr = t >> 1, sc = (t & 1) * 16;
    f32x4 acc[4][4] = {};
    for (int k0 = 0; k0 < 256; k0 += 32) {
        *(bf16x8*)&As[sr][sc]     = *(const bf16x8*)&A[(size_t)(m0 + sr) * 256 + k0 + sc];
        *(bf16x8*)&As[sr][sc + 8] = *(const bf16x8*)&A[(size_t)(m0 + sr) * 256 + k0 + sc + 8];
        *(bf16x8*)&Bs[sr][sc]     = *(const bf16x8*)&WT[(size_t)(ybase + sr) * 256 + k0 + sc];
        *(bf16x8*)&Bs[sr][sc + 8] = *(const bf16x8*)&WT[(size_t)(ybase + sr) * 256 + k0 + sc + 8];
        __syncthreads();
        bf16x8 a[4], b[4];
        #pragma unroll
        for (int i = 0; i < 4; ++i) {
            a[i] = *(const bf16x8*)&As[wr * 64 + i * 16 + lane16][quad * 8];
            b[i] = *(const bf16x8*)&Bs[wc * 64 + i * 16 + lane16][quad * 8];
        }
        #pragma unroll
        for (int i = 0; i < 4; ++i)
            #pragma unroll
            for (int j = 0; j < 4; ++j)
                acc[i][j] = __builtin_amdgcn_mfma_f32_16x16x32_bf16(a[i], b[j], acc[i][j], 0, 0, 0);
        __syncthreads();
    }
    bf16* C; int N, cbase;
    if (ybase < 256)      { C = Cl;   N = 256; cbase = ybase; }
    else if (ybase < 384) { C = Cq1;  N = 128; cbase = ybase - 256; }
    else if (ybase < 512) { C = Cq2;  N = 128; cbase = ybase - 384; }
    else                  { C = Ckv2; N = 256; cbase = ybase - 512; }
    #pragma unroll
    for (int j = 0; j < 4; ++j) {
        int gcol = ybase + wc * 64 + j * 16 + lane16;
        float bv = b2f(bias[gcol]);
        int col = cbase + wc * 64 + j * 16 + lane16;
        #pragma unroll
        for (int i = 0; i < 4; ++i)
            #pragma unroll
            for (int r = 0; r < 4; ++r) {
                int row = m0 + wr * 64 + i * 16 + quad * 4 + r;
                C[(size_t)row * N + col] = f2b(acc[i][j][r] + bv);
            }
    }
}

// proj GEMM, 128x128 tile: out = 2*((attn+lepe) @ proj_w + bias). grid (128,2).
__global__ __launch_bounds__(256) void gemm_proj128(
    const bf16* __restrict__ A, const bf16* __restrict__ A2,
    const bf16* __restrict__ WT, const bf16* __restrict__ bias,
    void* __restrict__ dout, const int* __restrict__ flag)
{
    __shared__ bf16 As[128][40];
    __shared__ bf16 Bs[128][40];
    int t = threadIdx.x;
    int m0 = blockIdx.x * 128, n0 = blockIdx.y * 128;
    int w = t >> 6, l = t & 63, lane16 = l & 15, quad = l >> 4;
    int wr = w >> 1, wc = w & 1;
    int sr = t >> 1, sc = (t & 1) * 16;
    f32x4 acc[4][4] = {};
    for (int k0 = 0; k0 < 256; k0 += 32) {
        #pragma unroll
        for (int hh = 0; hh < 2; ++hh) {
            bf16x8 va = *(const bf16x8*)&A[(size_t)(m0 + sr) * 256 + k0 + sc + hh * 8];
            bf16x8 vb = *(const bf16x8*)&A2[(size_t)(m0 + sr) * 256 + k0 + sc + hh * 8];
            bf16 tmp[8];
            #pragma unroll
            for (int q = 0; q < 8; ++q) tmp[q] = f2b(s2f(va[q]) + s2f(vb[q]));
            *(bf16x8*)&As[sr][sc + hh * 8] = *(bf16x8*)tmp;
        }
        *(bf16x8*)&Bs[sr][sc]     = *(const bf16x8*)&WT[(size_t)(n0 + sr) * 256 + k0 + sc];
        *(bf16x8*)&Bs[sr][sc + 8] = *(const bf16x8*)&WT[(size_t)(n0 + sr) * 256 + k0 + sc + 8];
        __syncthreads();
        bf16x8 a[4], b[4];
        #pragma unroll
        for (int i = 0; i < 4; ++i) {
            a[i] = *(const bf16x8*)&As[wr * 64 + i * 16 + lane16][quad * 8];
            b[i] = *(const bf16x8*)&Bs[wc * 64 + i * 16 + lane16][quad * 8];
        }
        #pragma unroll
        for (int i = 0; i < 4; ++i)
            #pragma unroll
            for (int j = 0; j < 4; ++j)
                acc[i][j] = __builtin_amdgcn_mfma_f32_16x16x32_bf16(a[i], b[j], acc[i][j], 0, 0, 0);
        __syncthreads();
    }
    #pragma unroll
    for (int j = 0; j < 4; ++j) {
        int col = n0 + wc * 64 + j * 16 + lane16;
        float bv = b2f(bias[col]);
        #pragma unroll
        for (int i = 0; i < 4; ++i)
            #pragma unroll
            for (int r = 0; r < 4; ++r) {
                int row = m0 + wr * 64 + i * 16 + quad * 4 + r;
                float rv = (acc[i][j][r] + bv) * 2.f;
                size_t o = (size_t)row * 256 + col;
                if (*flag) ((float*)dout)[o] = rv;
                else       ((bf16*)dout)[o] = f2b(rv);
            }
    }
}

// sr conv as MFMA GEMM with gathered A rows. M=4096, N=256, K=1024. (r4-verified)
__global__ __launch_bounds__(256) void gemm_sr_mfma(
    const bf16* __restrict__ x, const bf16* __restrict__ WT,
    const bf16* __restrict__ bias, bf16* __restrict__ C)
{
    __shared__ bf16 As[64][40];
    __shared__ bf16 Bs[64][40];
    int t = threadIdx.x;
    int m0 = blockIdx.x * 64, n0 = blockIdx.y * 64;
    int w = t >> 6, l = t & 63, lane16 = l & 15, quad = l >> 4;
    int sr = t >> 2, sc = (t & 3) * 8;
    int brow = m0 + sr;
    int b = brow >> 10, p = brow & 1023;
    int pi = p >> 5, pj = p & 31;
    f32x4 acc[4] = {};
    for (int k0 = 0; k0 < 1024; k0 += 32) {
        int kg = k0 + sc;
        int e = kg >> 8, ci = kg & 255;
        int di = e >> 1, dj = e & 1;
        int n = (2 * pi + di) * 64 + 2 * pj + dj;
        *(bf16x8*)&As[sr][sc] = *(const bf16x8*)&x[(size_t)((b << 12) + n) * 256 + ci];
        *(bf16x8*)&Bs[sr][sc] = *(const bf16x8*)&WT[(size_t)(n0 + sr) * 1024 + kg];
        __syncthreads();
        bf16x8 a = *(const bf16x8*)&As[w * 16 + lane16][quad * 8];
        #pragma unroll
        for (int ct = 0; ct < 4; ++ct) {
            bf16x8 bb = *(const bf16x8*)&Bs[ct * 16 + lane16][quad * 8];
            acc[ct] = __builtin_amdgcn_mfma_f32_16x16x32_bf16(a, bb, acc[ct], 0, 0, 0);
        }
        __syncthreads();
    }
    #pragma unroll
    for (int ct = 0; ct < 4; ++ct) {
        int col = n0 + ct * 16 + lane16;
        float bv = b2f(bias[col]);
        #pragma unroll
        for (int r = 0; r < 4; ++r) {
            int row = m0 + w * 16 + quad * 4 + r;
            C[(size_t)row * 256 + col] = f2b(acc[ct][r] + bv);
        }
    }
}

// kv1 GEMM: xs[4096,256] @ kv1_w + b; K-half -> k1[b,key,h,ch] (stride 128),
// V-half transposed -> v1T[b,h,ch,key]. (r5-verified)
__global__ __launch_bounds__(256) void gemm_kv1(
    const bf16* __restrict__ A, const bf16* __restrict__ WT, const bf16* __restrict__ bias,
    bf16* __restrict__ k1, bf16* __restrict__ v1T)
{
    __shared__ bf16 As[64][40];
    __shared__ bf16 Bs[64][40];
    int t = threadIdx.x;
    int m0 = blockIdx.x * 64, n0 = blockIdx.y * 64;
    int w = t >> 6, l = t & 63, lane16 = l & 15, quad = l >> 4;
    int sr = t >> 2, sc = (t & 3) * 8;
    f32x4 acc[4] = {};
    for (int k0 = 0; k0 < 256; k0 += 32) {
        *(bf16x8*)&As[sr][sc] = *(const bf16x8*)&A[(size_t)(m0 + sr) * 256 + k0 + sc];
        *(bf16x8*)&Bs[sr][sc] = *(const bf16x8*)&WT[(size_t)(n0 + sr) * 256 + k0 + sc];
        __syncthreads();
        bf16x8 a = *(const bf16x8*)&As[w * 16 + lane16][quad * 8];
        #pragma unroll
        for (int ct = 0; ct < 4; ++ct) {
            bf16x8 b = *(const bf16x8*)&Bs[ct * 16 + lane16][quad * 8];
            acc[ct] = __builtin_amdgcn_mfma_f32_16x16x32_bf16(a, b, acc[ct], 0, 0, 0);
        }
        __syncthreads();
    }
    #pragma unroll
    for (int ct = 0; ct < 4; ++ct) {
        int col = n0 + ct * 16 + lane16;
        float bv = b2f(bias[col]);
        #pragma unroll
        for (int r = 0; r < 4; ++r) {
            int row = m0 + w * 16 + quad * 4 + r;
            float val = acc[ct][r] + bv;
            int bb = row >> 10, key = row & 1023;
            if (col < 128) {
                k1[(size_t)row * 128 + col] = f2b(val);
            } else {
                int h = (col - 128) >> 5, ch = (col - 128) & 31;
                v1T[(size_t)((bb * 4 + h) * 32 + ch) * 1024 + key] = f2b(val);
            }
        }
    }
}

// ---------------------------------------------------------------------------
// depthwise 3x3, vectorized: one thread per 8 channels.
// ---------------------------------------------------------------------------
__global__ __launch_bounds__(256) void dwconv3v(
    const bf16* __restrict__ lin, const bf16* __restrict__ dwT,
    const bf16* __restrict__ bias, bf16* __restrict__ out)
{
    int tid = blockIdx.x * 256 + threadIdx.x;   // 524288
    int c0 = (tid & 31) * 8;
    int n = (tid >> 5) & 4095;
    int b = tid >> 17;
    int i = n >> 6, j = n & 63;
    float acc[8];
    bf16x8 bv = *(const bf16x8*)&bias[c0];
    #pragma unroll
    for (int q = 0; q < 8; ++q) acc[q] = s2f(bv[q]);
    #pragma unroll
    for (int di = 0; di < 3; ++di) {
        int ii = i + di - 1;
        if (ii < 0 || ii > 63) continue;
        #pragma unroll
        for (int dj = 0; dj < 3; ++dj) {
            int jj = j + dj - 1;
            if (jj < 0 || jj > 63) continue;
            bf16x8 xv = *(const bf16x8*)&lin[(size_t)((b << 12) + ii * 64 + jj) * 256 + c0];
            bf16x8 wv = *(const bf16x8*)&dwT[(di * 3 + dj) * 256 + c0];
            #pragma unroll
            for (int q = 0; q < 8; ++q) acc[q] += s2f(xv[q]) * s2f(wv[q]);
        }
    }
    bf16 ov[8];
    #pragma unroll
    for (int q = 0; q < 8; ++q) ov[q] = f2b(acc[q]);
    *(bf16x8*)&out[(size_t)((b << 12) + n) * 256 + c0] = *(bf16x8*)ov;
}

// ---------------------------------------------------------------------------
// layernorm+gelu, one wave per row (4 ch/lane).
// ---------------------------------------------------------------------------
__global__ __launch_bounds__(256) void ln_gelu_w(
    const bf16* __restrict__ xin, const bf16* __restrict__ nw,
    const bf16* __restrict__ nb, bf16* __restrict__ xout)
{
    int w = threadIdx.x >> 6, lane = threadIdx.x & 63;
    int r = blockIdx.x * 4 + w;
    bf16x4 xv = *(const bf16x4*)&xin[(size_t)r * 256 + lane * 4];
    float v[4];
    #pragma unroll
    for (int j = 0; j < 4; ++j) v[j] = s2f(xv[j]);
    float s = v[0] + v[1] + v[2] + v[3];
    #pragma unroll
    for (int o = 1; o <= 32; o <<= 1) s += __shfl_xor(s, o);
    float mean = s * (1.f / 256.f);
    float ss = 0.f;
    #pragma unroll
    for (int j = 0; j < 4; ++j) { float d = v[j] - mean; ss += d * d; }
    #pragma unroll
    for (int o = 1; o <= 32; o <<= 1) ss += __shfl_xor(ss, o);
    float inv = rsqrtf(ss * (1.f / 256.f) + 1e-5f);
    bf16x4 wv = *(const bf16x4*)&nw[lane * 4];
    bf16x4 bv = *(const bf16x4*)&nb[lane * 4];
    bf16 ov[4];
    #pragma unroll
    for (int j = 0; j < 4; ++j) {
        float y = (v[j] - mean) * inv * s2f(wv[j]) + s2f(bv[j]);
        ov[j] = f2b(0.5f * y * (1.f + erff(y * 0.70710678118654752f)));
    }
    *(bf16x4*)&xout[(size_t)r * 256 + lane * 4] = *(bf16x4*)ov;
}

// ---------------------------------------------------------------------------
// Branch-1 attention, split-key flash. Block = 512 thr (8 waves), grid 1024.
// Wave w: group g = w>>2 handles keys [g*512, g*512+512); qg = w&3 handles
// queries 16*qg..16*qg+15. LDS-staged K (key-major) and V^T (ch-major);
// S^T = mfma(Kfrag, Qfrag) -> packed b64 PTT writes (wave-private);
// PV: O^T += mfma(Vfrag, Pfrag), unnormalized; l accumulated per lane.
// Additive combine (no-max softmax): l = l0+l1, O = (O0+O1)*1/l via LDS.
// Sweep 2 (g col sums) uses rl from LDS, S orientation mfma(Q,K) (r5-verified).
// ---------------------------------------------------------------------------
__global__ __launch_bounds__(512) void attn1_split(
    const bf16* __restrict__ q1, const bf16* __restrict__ k1,
    const bf16* __restrict__ v1T, bf16* __restrict__ attn_out, float* __restrict__ g)
{
    __shared__ bf16 Kt[2][64][40];      // per-group K tile (key-major)
    __shared__ bf16 Vt[2][32][68];      // per-group V^T tile (ch-major)
    __shared__ bf16 PTT[8][16][72];     // per-wave P^T strip [q][k]
    __shared__ float gp[1024];
    __shared__ float Lcmb[4][16];       // group-1 partial l
    __shared__ float rls[4][16];        // final 1/l per (qg, q)
    __shared__ __align__(16) float Ocmb[4][16][36]; // group-1 partial O^T

    int t = threadIdx.x;
    int blk = blockIdx.x;
    int qc = blk & 63, h = (blk >> 6) & 3, b = blk >> 8;
    int n0 = qc * 64;
    int w = t >> 6, l = t & 63, lane16 = l & 15, quad = l >> 4;
    int grp = w >> 2, qg = w & 3;
    int tg = t & 255;                    // group-local thread id
    const float scale = 0.17677669529663687f;   // 1/sqrt(32)

    const bf16* Kbase = k1 + (size_t)b * 1024 * 128 + 32 * h + (size_t)(grp * 512) * 128;
    const bf16* Vbase = v1T + (size_t)((b * 4 + h) * 32) * 1024 + grp * 512;
    bf16x8 qa = *(const bf16x8*)&q1[(size_t)(b * 4096 + n0 + 16 * qg + lane16) * 128 + 32 * h + quad * 8];

    for (int i = t; i < 1024; i += 512) gp[i] = 0.f;

    int sr = tg >> 2, sc = (tg & 3) * 8;        // K staging: 64 rows x 32
    int vrow = tg >> 3, vcol = (tg & 7) * 8;    // V staging: 32 rows x 64
    bf16* ptt = &PTT[w][0][0];

    float lacc = 0.f;
    f32x4 oT0 = {}, oT1 = {};

    // ---- sweep 1 over this group's 8 key tiles ----
    for (int ktl = 0; ktl < 8; ++ktl) {
        *(bf16x8*)&Kt[grp][sr][sc] = *(const bf16x8*)&Kbase[(size_t)(ktl * 64 + sr) * 128 + sc];
        *(bf16x8*)&Vt[grp][vrow][vcol] = *(const bf16x8*)&Vbase[(size_t)vrow * 1024 + ktl * 64 + vcol];
        __syncthreads();
        #pragma unroll
        for (int st = 0; st < 4; ++st) {
            bf16x8 kf = *(const bf16x8*)&Kt[grp][st * 16 + lane16][quad * 8];
            f32x4 z = {0.f, 0.f, 0.f, 0.f};
            f32x4 sT = __builtin_amdgcn_mfma_f32_16x16x32_bf16(kf, qa, z, 0, 0, 0);
            bf16 pk[4];
            #pragma unroll
            for (int r = 0; r < 4; ++r) {
                float p = __expf(sT[r] * scale);
                lacc += p;
                pk[r] = f2b(p);
            }
            *(bf16x4*)&ptt[lane16 * 72 + st * 16 + quad * 4] = *(bf16x4*)pk;
        }
        #pragma unroll
        for (int kh = 0; kh < 2; ++kh) {
            bf16x8 pf = *(const bf16x8*)&ptt[lane16 * 72 + kh * 32 + quad * 8];
            bf16x8 vf0 = *(const bf16x8*)&Vt[grp][lane16][kh * 32 + quad * 8];
            bf16x8 vf1 = *(const bf16x8*)&Vt[grp][16 + lane16][kh * 32 + quad * 8];
            oT0 = __builtin_amdgcn_mfma_f32_16x16x32_bf16(vf0, pf, oT0, 0, 0, 0);
            oT1 = __builtin_amdgcn_mfma_f32_16x16x32_bf16(vf1, pf, oT1, 0, 0, 0);
        }
        __syncthreads();
    }

    // partial l for q = lane16 (sum over quads)
    lacc += __shfl_xor(lacc, 16);
    lacc += __shfl_xor(lacc, 32);

    // ---- combine halves ----
    if (grp == 1) {
        if (quad == 0) Lcmb[qg][lane16] = lacc;
        *(f32x4*)&Ocmb[qg][lane16][quad * 4]      = oT0;
        *(f32x4*)&Ocmb[qg][lane16][16 + quad * 4] = oT1;
    }
    __syncthreads();
    if (grp == 0) {
        float ltot = lacc + Lcmb[qg][lane16];
        float rl = 1.f / ltot;
        if (quad == 0) rls[qg][lane16] = rl;
        f32x4 p0 = *(const f32x4*)&Ocmb[qg][lane16][quad * 4];
        f32x4 p1 = *(const f32x4*)&Ocmb[qg][lane16][16 + quad * 4];
        bf16 ov0[4], ov1[4];
        #pragma unroll
        for (int r = 0; r < 4; ++r) {
            ov0[r] = f2b((oT0[r] + p0[r]) * rl);
            ov1[r] = f2b((oT1[r] + p1[r]) * rl);
        }
        size_t ro = (size_t)(b * 4096 + n0 + 16 * qg + lane16) * 256 + 32 * h;
        *(bf16x4*)&attn_out[ro + quad * 4]      = *(bf16x4*)ov0;
        *(bf16x4*)&attn_out[ro + 16 + quad * 4] = *(bf16x4*)ov1;
    }
    __syncthreads();

    float rlq[4];
    #pragma unroll
    for (int r = 0; r < 4; ++r) rlq[r] = rls[qg][quad * 4 + r];

    // ---- sweep 2: g column sums (normalized) over this group's keys ----
    int sr2 = tg >> 2, sc2 = (tg & 3) * 8;
    for (int ktl = 0; ktl < 8; ++ktl) {
        *(bf16x8*)&Kt[grp][sr2][sc2] = *(const bf16x8*)&Kbase[(size_t)(ktl * 64 + sr2) * 128 + sc2];
        __syncthreads();
        #pragma unroll
        for (int st = 0; st < 4; ++st) {
            bf16x8 kf = *(const bf16x8*)&Kt[grp][st * 16 + lane16][quad * 8];
            f32x4 z = {0.f, 0.f, 0.f, 0.f};
            f32x4 s = __builtin_amdgcn_mfma_f32_16x16x32_bf16(qa, kf, z, 0, 0, 0);
            float cs = 0.f;
            #pragma unroll
            for (int r = 0; r < 4; ++r) cs += __expf(s[r] * scale) * rlq[r];
            cs += __shfl_xor(cs, 16);
            cs += __shfl_xor(cs, 32);
            if (quad == 0) atomicAdd(&gp[grp * 512 + ktl * 64 + st * 16 + lane16], cs);
        }
        __syncthreads();
    }

    for (int i = t; i < 1024; i += 512)
        atomicAdd(&g[(b << 10) + i], gp[i] * (1.f / 16384.f));
}

// ---------------------------------------------------------------------------
// Branch-2 windowed attention, vectorized loads (r5-verified).
// ---------------------------------------------------------------------------
__global__ __launch_bounds__(64) void attn2_vec(
    const bf16* __restrict__ q2, const bf16* __restrict__ kv2,
    bf16* __restrict__ attn_out, float* __restrict__ lm)
{
    __shared__ float P2[64][17];
    int t = threadIdx.x;
    int blk = blockIdx.x;
    int b = blk >> 8, win = blk & 255;
    int wi = win >> 4, wj = win & 15;
    int h = t >> 4, qi = t & 15;
    int nq = (wi * 4 + (qi >> 2)) * 64 + wj * 4 + (qi & 3);

    float qv[32];
    {
        const bf16* qp = q2 + (size_t)(b * 4096 + nq) * 128 + h * 32;
        #pragma unroll
        for (int g8 = 0; g8 < 4; ++g8) {
            bf16x8 v = *(const bf16x8*)&qp[g8 * 8];
            #pragma unroll
            for (int j = 0; j < 8; ++j) qv[g8 * 8 + j] = s2f(v[j]) * 0.17677669529663687f;
        }
    }
    float s[16];
    float mx = -1e30f;
    #pragma unroll
    for (int k = 0; k < 16; ++k) {
        int nk = (wi * 4 + (k >> 2)) * 64 + wj * 4 + (k & 3);
        const bf16* kp = kv2 + (size_t)(b * 4096 + nk) * 256 + h * 32;
        float ss = 0.f;
        #pragma unroll
        for (int g8 = 0; g8 < 4; ++g8) {
            bf16x8 v = *(const bf16x8*)&kp[g8 * 8];
            #pragma unroll
            for (int j = 0; j < 8; ++j) ss += qv[g8 * 8 + j] * s2f(v[j]);
        }
        s[k] = ss;
        mx = fmaxf(mx, ss);
    }
    float lsum = 0.f;
    #pragma unroll
    for (int k = 0; k < 16; ++k) { s[k] = __expf(s[k] - mx); lsum += s[k]; }
    float rl = 1.f / lsum;
    #pragma unroll
    for (int k = 0; k < 16; ++k) s[k] *= rl;

    float o[32];
    #pragma unroll
    for (int d = 0; d < 32; ++d) o[d] = 0.f;
    #pragma unroll
    for (int k = 0; k < 16; ++k) {
        int nk = (wi * 4 + (k >> 2)) * 64 + wj * 4 + (k & 3);
        const bf16* vp = kv2 + (size_t)(b * 4096 + nk) * 256 + 128 + h * 32;
        float p = s[k];
        #pragma unroll
        for (int g8 = 0; g8 < 4; ++g8) {
            bf16x8 v = *(const bf16x8*)&vp[g8 * 8];
            #pragma unroll
            for (int j = 0; j < 8; ++j) o[g8 * 8 + j] += p * s2f(v[j]);
        }
    }
    {
        bf16* op = attn_out + (size_t)(b * 4096 + nq) * 256 + 128 + h * 32;
        #pragma unroll
        for (int g8 = 0; g8 < 4; ++g8) {
            bf16 ov[8];
            #pragma unroll
            for (int j = 0; j < 8; ++j) ov[j] = f2b(o[g8 * 8 + j]);
            *(bf16x8*)&op[g8 * 8] = *(bf16x8*)ov;
        }
    }

    #pragma unroll
    for (int k = 0; k < 16; ++k) P2[t][k] = s[k];
    __syncthreads();
    if (t < 16) {
        float cs = 0.f;
        for (int qq = 0; qq < 64; ++qq) cs += P2[qq][t];
        int nk = (wi * 4 + (t >> 2)) * 64 + wj * 4 + (t & 3);
        lm[(b << 12) + nk] = cs * (1.f / 64.f);
    }
}

// ---------------------------------------------------------------------------
__global__ void mask_combine(const float* __restrict__ lm, const float* __restrict__ g,
                             void* __restrict__ dout, const int* __restrict__ flag)
{
    int tid = blockIdx.x * 256 + threadIdx.x;   // 16384
    int b = tid >> 12, n = tid & 4095;
    int i = n >> 6, j = n & 63;
    float v = lm[tid] + g[(b << 10) + (i >> 1) * 32 + (j >> 1)];
    size_t o1 = (size_t)4194304 + (b << 12) + i * 64 + j;
    size_t o2 = (size_t)4194304 + 16384 + (b << 12) + j * 64 + i;
    if (*flag) { ((float*)dout)[o1] = v; ((float*)dout)[o2] = v; }
    else       { ((bf16*)dout)[o1] = f2b(v); ((bf16*)dout)[o2] = f2b(v); }
}

// ---------------------------------------------------------------------------
extern "C" void kernel_launch(void* const* d_in, const int* in_sizes, int n_in,
                              void* d_out, int out_size, void* d_ws, size_t ws_size,
                              hipStream_t stream)
{
    char* ws = (char*)d_ws;
    size_t off = 0;
    auto alloc = [&](size_t bytes) {
        void* p = ws + off;
        off += (bytes + 255) & ~(size_t)255;
        return p;
    };
    bf16* cx       = (bf16*)alloc((size_t)4194304 * 2);
    bf16* lepe_lin = (bf16*)alloc((size_t)4194304 * 2);   // reused as attn_out
    bf16* attn_out = lepe_lin;
    bf16* lepe     = (bf16*)alloc((size_t)4194304 * 2);
    bf16* q1buf    = (bf16*)alloc((size_t)2097152 * 2);
    bf16* q2buf    = (bf16*)alloc((size_t)2097152 * 2);
    bf16* kv2buf   = (bf16*)alloc((size_t)4194304 * 2);
    bf16* xs_pre   = (bf16*)alloc((size_t)1048576 * 2);   // later reused: k1 + v1T
    bf16* k1buf    = xs_pre;                               // 524288 elems
    bf16* v1Tbuf   = xs_pre + 524288;                      // 524288 elems
    bf16* xs       = (bf16*)alloc((size_t)1048576 * 2);
    bf16* wTqkv    = (bf16*)alloc((size_t)196608 * 2);     // 768 x 256
    bf16* kv1_wT   = (bf16*)alloc(65536 * 2);
    bf16* proj_wT  = (bf16*)alloc(65536 * 2);
    bf16* sr_wT    = (bf16*)alloc(262144 * 2);
    bf16* dwT      = (bf16*)alloc(2304 * 2);
    bf16* bcat     = (bf16*)alloc(768 * 2);
    bf16* ckv1b    = (bf16*)alloc(256 * 2);
    bf16* csrb     = (bf16*)alloc(256 * 2);
    bf16* cnw      = (bf16*)alloc(256 * 2);
    bf16* cnb      = (bf16*)alloc(256 * 2);
    bf16* cpb      = (bf16*)alloc(256 * 2);
    bf16* clcb     = (bf16*)alloc(256 * 2);
    float* gbuf    = (float*)alloc(4096 * 4);
    float* lmbuf   = (float*)alloc(16384 * 4);
    int*   flag    = (int*)alloc(256);

    detect_dtype<<<1, 256, 0, stream>>>(d_in[0], flag);

    convert_x4<<<4096, 256, 0, stream>>>(d_in[0], cx, flag);

    PackArgs pa;
    pa.src[0] = d_in[10]; pa.dst[0] = bcat;       pa.n[0] = 256;  // lepe_b
    pa.src[1] = d_in[2];  pa.dst[1] = bcat + 256; pa.n[1] = 128;  // q1_b
    pa.src[2] = d_in[6];  pa.dst[2] = bcat + 384; pa.n[2] = 128;  // q2_b
    pa.src[3] = d_in[8];  pa.dst[3] = bcat + 512; pa.n[3] = 256;  // kv2_b
    pa.src[4] = d_in[4];  pa.dst[4] = ckv1b;      pa.n[4] = 256;
    pa.src[5] = d_in[14]; pa.dst[5] = csrb;       pa.n[5] = 256;
    pa.src[6] = d_in[15]; pa.dst[6] = cnw;        pa.n[6] = 256;
    pa.src[7] = d_in[16]; pa.dst[7] = cnb;        pa.n[7] = 256;
    pa.src[8] = d_in[18]; pa.dst[8] = cpb;        pa.n[8] = 256;
    pa.src[9] = d_in[12]; pa.dst[9] = clcb;       pa.n[9] = 256;
    pack_small<<<10, 256, 0, stream>>>(pa, flag);

    WTArgs wa;
    wa.src[0] = d_in[9];  wa.dst[0] = wTqkv;             wa.N[0] = 256;
    wa.src[1] = d_in[1];  wa.dst[1] = wTqkv + 256 * 256; wa.N[1] = 128;
    wa.src[2] = d_in[5];  wa.dst[2] = wTqkv + 384 * 256; wa.N[2] = 128;
    wa.src[3] = d_in[7];  wa.dst[3] = wTqkv + 512 * 256; wa.N[3] = 256;
    wa.src[4] = d_in[3];  wa.dst[4] = kv1_wT;            wa.N[4] = 256;
    wa.src[5] = d_in[17]; wa.dst[5] = proj_wT;           wa.N[5] = 256;
    int bo[7] = {0, 256, 384, 512, 768, 1024, 1280};
    for (int i = 0; i < 7; ++i) wa.blkoff[i] = bo[i];
    convert_wT_multi<<<1280, 256, 0, stream>>>(wa, flag);

    convert_srwT<<<1024, 256, 0, stream>>>(d_in[13], sr_wT, flag);
    convert_dwT<<<9, 256, 0, stream>>>(d_in[11], dwT, flag);

    hipMemsetAsync(gbuf, 0, 4096 * 4, stream);

    // fused x-projections (128x128 tile)
    gemm_qkv128<<<dim3(128, 6), 256, 0, stream>>>(cx, wTqkv, bcat, lepe_lin, q1buf, q2buf, kv2buf);
    // spatial reduction branch
    gemm_sr_mfma<<<dim3(64, 4), 256, 0, stream>>>(cx, sr_wT, csrb, xs_pre);
    ln_gelu_w<<<1024, 256, 0, stream>>>(xs_pre, cnw, cnb, xs);
    gemm_kv1<<<dim3(64, 4), 256, 0, stream>>>(xs, kv1_wT, ckv1b, k1buf, v1Tbuf);
    // lepe (consumes lepe_lin; must precede attn kernels which reuse that slot)
    dwconv3v<<<2048, 256, 0, stream>>>(lepe_lin, dwT, clcb, lepe);
    // attentions
    attn1_split<<<1024, 512, 0, stream>>>(q1buf, k1buf, v1Tbuf, attn_out, gbuf);
    attn2_vec<<<1024, 64, 0, stream>>>(q2buf, kv2buf, attn_out, lmbuf);
    // projection epilogue (128x128 tile)
    gemm_proj128<<<dim3(128, 2), 256, 0, stream>>>(attn_out, lepe, proj_wT, cpb, d_out, flag);
    // masks
    mask_combine<<<64, 256, 0, stream>>>(lmbuf, gbuf, d_out, flag);
}

// Round 8
// 253.957 us; speedup vs baseline: 1.1729x; 1.0564x over previous
//
#include <hip/hip_runtime.h>
#include <hip/hip_bf16.h>
#include <math.h>

typedef __hip_bfloat16 bf16;
typedef __attribute__((ext_vector_type(8))) short bf16x8;
typedef __attribute__((ext_vector_type(4))) short bf16x4;
typedef __attribute__((ext_vector_type(4))) float f32x4;

__device__ __forceinline__ float b2f(bf16 v) { return __bfloat162float(v); }
__device__ __forceinline__ bf16  f2b(float v) { return __float2bfloat16(v); }
__device__ __forceinline__ float s2f(short v) { return __uint_as_float(((unsigned)(unsigned short)v) << 16); }

// ---------------------------------------------------------------------------
// Input dtype detection: 1 = fp32 buffers, 0 = bf16 buffers.
// ---------------------------------------------------------------------------
__global__ void detect_dtype(const void* x, int* flag)
{
    __shared__ int cnt;
    if (threadIdx.x == 0) cnt = 0;
    __syncthreads();
    const unsigned* w = (const unsigned*)x;
    int sane = 0;
    for (int i = threadIdx.x; i < 2048; i += 256) {
        unsigned lo = (w[i] & 0xFFFFu) << 16;
        float v = __uint_as_float(lo);
        float a = fabsf(v);
        if (v == 0.f || (a > 1e-8f && a < 1e4f)) sane++;
    }
    atomicAdd(&cnt, sane);
    __syncthreads();
    if (threadIdx.x == 0) *flag = (cnt < 1640) ? 1 : 0;
}

// x convert, 4 elems/thread
__global__ void convert_x4(const void* __restrict__ src, bf16* __restrict__ dst,
                           const int* __restrict__ flag)
{
    int i = blockIdx.x * 256 + threadIdx.x;   // 1048576 quads
    bf16 tmp[4];
    if (*flag) {
        float4 v = ((const float4*)src)[i];
        tmp[0] = f2b(v.x); tmp[1] = f2b(v.y); tmp[2] = f2b(v.z); tmp[3] = f2b(v.w);
        *(bf16x4*)&dst[i * 4] = *(bf16x4*)tmp;
    } else {
        ((bf16x4*)dst)[i] = ((const bf16x4*)src)[i];
    }
}

// ---------------------------------------------------------------------------
// Merged misc converts: blocks [0,1024) srwT, [1024,1033) dwT, [1033,1043) small.
// ---------------------------------------------------------------------------
struct MiscArgs {
    const void* srw;  bf16* srwT;
    const void* dww;  bf16* dwT;
    const void* psrc[10]; bf16* pdst[10]; int pn[10];
};
__global__ void convert_misc(MiscArgs a, const int* __restrict__ flag)
{
    int blk = blockIdx.x, t = threadIdx.x;
    int fl = *flag;
    if (blk < 1024) {
        // sr_w (256co, 256ci, 2, 2) -> WT[co*1024 + (e*256+ci)]
        int o = blk * 256 + t;
        int co = o >> 10, kg = o & 1023;
        int e = kg >> 8, ci = kg & 255;
        int si = co * 1024 + ci * 4 + e;
        float v = fl ? ((const float*)a.srw)[si] : s2f(((const short*)a.srw)[si]);
        a.srwT[o] = f2b(v);
    } else if (blk < 1033) {
        // lepe_conv_w (256c,9) -> dwT[k*256+c]
        int o = (blk - 1024) * 256 + t;
        if (o >= 2304) return;
        int k = o >> 8, c = o & 255;
        float v = fl ? ((const float*)a.dww)[c * 9 + k] : s2f(((const short*)a.dww)[c * 9 + k]);
        a.dwT[o] = f2b(v);
    } else {
        int bi = blk - 1033;
        int n = a.pn[bi];
        const void* s = a.psrc[bi];
        bf16* d = a.pdst[bi];
        for (int i = t; i < n; i += 256)
            d[i] = fl ? f2b(((const float*)s)[i]) : f2b(s2f(((const short*)s)[i]));
    }
}

// six (K=256,N) weights -> WT[n*256+k], one launch
struct WTArgs { const void* src[6]; bf16* dst[6]; int N[6]; int blkoff[7]; };
__global__ void convert_wT_multi(WTArgs a, const int* __restrict__ flag)
{
    int blk = blockIdx.x;
    int ti = 0;
    while (blk >= a.blkoff[ti + 1]) ++ti;
    int o = (blk - a.blkoff[ti]) * 256 + threadIdx.x;
    int n = o >> 8, k = o & 255;
    int N = a.N[ti];
    float v = (*flag) ? ((const float*)a.src[ti])[k * N + n]
                      : s2f(((const short*)a.src[ti])[k * N + n]);
    a.dst[ti][o] = f2b(v);
}

// ---------------------------------------------------------------------------
// 128x128-tile MFMA GEMM for the fused QKV projection. M=16384, K=256.
// ---------------------------------------------------------------------------
__global__ __launch_bounds__(256) void gemm_qkv128(
    const bf16* __restrict__ A, const bf16* __restrict__ WT, const bf16* __restrict__ bias,
    bf16* __restrict__ Cl, bf16* __restrict__ Cq1, bf16* __restrict__ Cq2, bf16* __restrict__ Ckv2)
{
    __shared__ bf16 As[128][40];
    __shared__ bf16 Bs[128][40];
    int t = threadIdx.x;
    int m0 = blockIdx.x * 128, ybase = blockIdx.y * 128;
    int w = t >> 6, l = t & 63, lane16 = l & 15, quad = l >> 4;
    int wr = w >> 1, wc = w & 1;
    int sr = t >> 1, sc = (t & 1) * 16;
    f32x4 acc[4][4] = {};
    for (int k0 = 0; k0 < 256; k0 += 32) {
        *(bf16x8*)&As[sr][sc]     = *(const bf16x8*)&A[(size_t)(m0 + sr) * 256 + k0 + sc];
        *(bf16x8*)&As[sr][sc + 8] = *(const bf16x8*)&A[(size_t)(m0 + sr) * 256 + k0 + sc + 8];
        *(bf16x8*)&Bs[sr][sc]     = *(const bf16x8*)&WT[(size_t)(ybase + sr) * 256 + k0 + sc];
        *(bf16x8*)&Bs[sr][sc + 8] = *(const bf16x8*)&WT[(size_t)(ybase + sr) * 256 + k0 + sc + 8];
        __syncthreads();
        bf16x8 a[4], b[4];
        #pragma unroll
        for (int i = 0; i < 4; ++i) {
            a[i] = *(const bf16x8*)&As[wr * 64 + i * 16 + lane16][quad * 8];
            b[i] = *(const bf16x8*)&Bs[wc * 64 + i * 16 + lane16][quad * 8];
        }
        #pragma unroll
        for (int i = 0; i < 4; ++i)
            #pragma unroll
            for (int j = 0; j < 4; ++j)
                acc[i][j] = __builtin_amdgcn_mfma_f32_16x16x32_bf16(a[i], b[j], acc[i][j], 0, 0, 0);
        __syncthreads();
    }
    bf16* C; int N, cbase;
    if (ybase < 256)      { C = Cl;   N = 256; cbase = ybase; }
    else if (ybase < 384) { C = Cq1;  N = 128; cbase = ybase - 256; }
    else if (ybase < 512) { C = Cq2;  N = 128; cbase = ybase - 384; }
    else                  { C = Ckv2; N = 256; cbase = ybase - 512; }
    #pragma unroll
    for (int j = 0; j < 4; ++j) {
        int gcol = ybase + wc * 64 + j * 16 + lane16;
        float bv = b2f(bias[gcol]);
        int col = cbase + wc * 64 + j * 16 + lane16;
        #pragma unroll
        for (int i = 0; i < 4; ++i)
            #pragma unroll
            for (int r = 0; r < 4; ++r) {
                int row = m0 + wr * 64 + i * 16 + quad * 4 + r;
                C[(size_t)row * N + col] = f2b(acc[i][j][r] + bv);
            }
    }
}

// proj GEMM, 128x128 tile: out = 2*((attn+lepe) @ proj_w + bias). grid (128,2).
__global__ __launch_bounds__(256) void gemm_proj128(
    const bf16* __restrict__ A, const bf16* __restrict__ A2,
    const bf16* __restrict__ WT, const bf16* __restrict__ bias,
    void* __restrict__ dout, const int* __restrict__ flag)
{
    __shared__ bf16 As[128][40];
    __shared__ bf16 Bs[128][40];
    int t = threadIdx.x;
    int m0 = blockIdx.x * 128, n0 = blockIdx.y * 128;
    int w = t >> 6, l = t & 63, lane16 = l & 15, quad = l >> 4;
    int wr = w >> 1, wc = w & 1;
    int sr = t >> 1, sc = (t & 1) * 16;
    f32x4 acc[4][4] = {};
    for (int k0 = 0; k0 < 256; k0 += 32) {
        #pragma unroll
        for (int hh = 0; hh < 2; ++hh) {
            bf16x8 va = *(const bf16x8*)&A[(size_t)(m0 + sr) * 256 + k0 + sc + hh * 8];
            bf16x8 vb = *(const bf16x8*)&A2[(size_t)(m0 + sr) * 256 + k0 + sc + hh * 8];
            bf16 tmp[8];
            #pragma unroll
            for (int q = 0; q < 8; ++q) tmp[q] = f2b(s2f(va[q]) + s2f(vb[q]));
            *(bf16x8*)&As[sr][sc + hh * 8] = *(bf16x8*)tmp;
        }
        *(bf16x8*)&Bs[sr][sc]     = *(const bf16x8*)&WT[(size_t)(n0 + sr) * 256 + k0 + sc];
        *(bf16x8*)&Bs[sr][sc + 8] = *(const bf16x8*)&WT[(size_t)(n0 + sr) * 256 + k0 + sc + 8];
        __syncthreads();
        bf16x8 a[4], b[4];
        #pragma unroll
        for (int i = 0; i < 4; ++i) {
            a[i] = *(const bf16x8*)&As[wr * 64 + i * 16 + lane16][quad * 8];
            b[i] = *(const bf16x8*)&Bs[wc * 64 + i * 16 + lane16][quad * 8];
        }
        #pragma unroll
        for (int i = 0; i < 4; ++i)
            #pragma unroll
            for (int j = 0; j < 4; ++j)
                acc[i][j] = __builtin_amdgcn_mfma_f32_16x16x32_bf16(a[i], b[j], acc[i][j], 0, 0, 0);
        __syncthreads();
    }
    #pragma unroll
    for (int j = 0; j < 4; ++j) {
        int col = n0 + wc * 64 + j * 16 + lane16;
        float bv = b2f(bias[col]);
        #pragma unroll
        for (int i = 0; i < 4; ++i)
            #pragma unroll
            for (int r = 0; r < 4; ++r) {
                int row = m0 + wr * 64 + i * 16 + quad * 4 + r;
                float rv = (acc[i][j][r] + bv) * 2.f;
                size_t o = (size_t)row * 256 + col;
                if (*flag) ((float*)dout)[o] = rv;
                else       ((bf16*)dout)[o] = f2b(rv);
            }
    }
}

// sr conv as MFMA GEMM with gathered A rows. M=4096, N=256, K=1024. (r4-verified)
__global__ __launch_bounds__(256) void gemm_sr_mfma(
    const bf16* __restrict__ x, const bf16* __restrict__ WT,
    const bf16* __restrict__ bias, bf16* __restrict__ C)
{
    __shared__ bf16 As[64][40];
    __shared__ bf16 Bs[64][40];
    int t = threadIdx.x;
    int m0 = blockIdx.x * 64, n0 = blockIdx.y * 64;
    int w = t >> 6, l = t & 63, lane16 = l & 15, quad = l >> 4;
    int sr = t >> 2, sc = (t & 3) * 8;
    int brow = m0 + sr;
    int b = brow >> 10, p = brow & 1023;
    int pi = p >> 5, pj = p & 31;
    f32x4 acc[4] = {};
    for (int k0 = 0; k0 < 1024; k0 += 32) {
        int kg = k0 + sc;
        int e = kg >> 8, ci = kg & 255;
        int di = e >> 1, dj = e & 1;
        int n = (2 * pi + di) * 64 + 2 * pj + dj;
        *(bf16x8*)&As[sr][sc] = *(const bf16x8*)&x[(size_t)((b << 12) + n) * 256 + ci];
        *(bf16x8*)&Bs[sr][sc] = *(const bf16x8*)&WT[(size_t)(n0 + sr) * 1024 + kg];
        __syncthreads();
        bf16x8 a = *(const bf16x8*)&As[w * 16 + lane16][quad * 8];
        #pragma unroll
        for (int ct = 0; ct < 4; ++ct) {
            bf16x8 bb = *(const bf16x8*)&Bs[ct * 16 + lane16][quad * 8];
            acc[ct] = __builtin_amdgcn_mfma_f32_16x16x32_bf16(a, bb, acc[ct], 0, 0, 0);
        }
        __syncthreads();
    }
    #pragma unroll
    for (int ct = 0; ct < 4; ++ct) {
        int col = n0 + ct * 16 + lane16;
        float bv = b2f(bias[col]);
        #pragma unroll
        for (int r = 0; r < 4; ++r) {
            int row = m0 + w * 16 + quad * 4 + r;
            C[(size_t)row * 256 + col] = f2b(acc[ct][r] + bv);
        }
    }
}

// kv1 GEMM: xs[4096,256] @ kv1_w + b; K-half -> k1[b,key,h,ch] (stride 128),
// V-half transposed -> v1T[b,h,ch,key]. (r5-verified)
__global__ __launch_bounds__(256) void gemm_kv1(
    const bf16* __restrict__ A, const bf16* __restrict__ WT, const bf16* __restrict__ bias,
    bf16* __restrict__ k1, bf16* __restrict__ v1T)
{
    __shared__ bf16 As[64][40];
    __shared__ bf16 Bs[64][40];
    int t = threadIdx.x;
    int m0 = blockIdx.x * 64, n0 = blockIdx.y * 64;
    int w = t >> 6, l = t & 63, lane16 = l & 15, quad = l >> 4;
    int sr = t >> 2, sc = (t & 3) * 8;
    f32x4 acc[4] = {};
    for (int k0 = 0; k0 < 256; k0 += 32) {
        *(bf16x8*)&As[sr][sc] = *(const bf16x8*)&A[(size_t)(m0 + sr) * 256 + k0 + sc];
        *(bf16x8*)&Bs[sr][sc] = *(const bf16x8*)&WT[(size_t)(n0 + sr) * 256 + k0 + sc];
        __syncthreads();
        bf16x8 a = *(const bf16x8*)&As[w * 16 + lane16][quad * 8];
        #pragma unroll
        for (int ct = 0; ct < 4; ++ct) {
            bf16x8 b = *(const bf16x8*)&Bs[ct * 16 + lane16][quad * 8];
            acc[ct] = __builtin_amdgcn_mfma_f32_16x16x32_bf16(a, b, acc[ct], 0, 0, 0);
        }
        __syncthreads();
    }
    #pragma unroll
    for (int ct = 0; ct < 4; ++ct) {
        int col = n0 + ct * 16 + lane16;
        float bv = b2f(bias[col]);
        #pragma unroll
        for (int r = 0; r < 4; ++r) {
            int row = m0 + w * 16 + quad * 4 + r;
            float val = acc[ct][r] + bv;
            int bb = row >> 10, key = row & 1023;
            if (col < 128) {
                k1[(size_t)row * 128 + col] = f2b(val);
            } else {
                int h = (col - 128) >> 5, ch = (col - 128) & 31;
                v1T[(size_t)((bb * 4 + h) * 32 + ch) * 1024 + key] = f2b(val);
            }
        }
    }
}

// ---------------------------------------------------------------------------
// depthwise 3x3, paired rows: one thread -> 8 channels x 2 tokens (i, i+1).
// Shares 6 of 9 input rows between the two outputs (18 -> 12 loads).
// ---------------------------------------------------------------------------
__global__ __launch_bounds__(256) void dwconv3p(
    const bf16* __restrict__ lin, const bf16* __restrict__ dwT,
    const bf16* __restrict__ bias, bf16* __restrict__ out)
{
    int tid = blockIdx.x * 256 + threadIdx.x;   // 262144
    int c0 = (tid & 31) * 8;
    int j  = (tid >> 5) & 63;
    int i  = ((tid >> 11) & 31) * 2;
    int b  = tid >> 16;
    float acc0[8], acc1[8];
    bf16x8 bv = *(const bf16x8*)&bias[c0];
    #pragma unroll
    for (int q = 0; q < 8; ++q) { acc0[q] = s2f(bv[q]); acc1[q] = s2f(bv[q]); }
    bf16x8 wv[3][3];
    #pragma unroll
    for (int di = 0; di < 3; ++di)
        #pragma unroll
        for (int dj = 0; dj < 3; ++dj)
            wv[di][dj] = *(const bf16x8*)&dwT[(di * 3 + dj) * 256 + c0];
    #pragma unroll
    for (int r = -1; r <= 2; ++r) {
        int ii = i + r;
        if (ii < 0 || ii > 63) continue;
        #pragma unroll
        for (int dj = 0; dj < 3; ++dj) {
            int jj = j + dj - 1;
            if (jj < 0 || jj > 63) continue;
            bf16x8 xv = *(const bf16x8*)&lin[(size_t)((b << 12) + ii * 64 + jj) * 256 + c0];
            if (r <= 1) {
                bf16x8 w0 = wv[r + 1][dj];
                #pragma unroll
                for (int q = 0; q < 8; ++q) acc0[q] += s2f(xv[q]) * s2f(w0[q]);
            }
            if (r >= 0) {
                bf16x8 w1 = wv[r][dj];
                #pragma unroll
                for (int q = 0; q < 8; ++q) acc1[q] += s2f(xv[q]) * s2f(w1[q]);
            }
        }
    }
    bf16 ov[8];
    #pragma unroll
    for (int q = 0; q < 8; ++q) ov[q] = f2b(acc0[q]);
    *(bf16x8*)&out[(size_t)((b << 12) + i * 64 + j) * 256 + c0] = *(bf16x8*)ov;
    #pragma unroll
    for (int q = 0; q < 8; ++q) ov[q] = f2b(acc1[q]);
    *(bf16x8*)&out[(size_t)((b << 12) + (i + 1) * 64 + j) * 256 + c0] = *(bf16x8*)ov;
}

// ---------------------------------------------------------------------------
// layernorm+gelu, one wave per row (4 ch/lane).
// ---------------------------------------------------------------------------
__global__ __launch_bounds__(256) void ln_gelu_w(
    const bf16* __restrict__ xin, const bf16* __restrict__ nw,
    const bf16* __restrict__ nb, bf16* __restrict__ xout)
{
    int w = threadIdx.x >> 6, lane = threadIdx.x & 63;
    int r = blockIdx.x * 4 + w;
    bf16x4 xv = *(const bf16x4*)&xin[(size_t)r * 256 + lane * 4];
    float v[4];
    #pragma unroll
    for (int j = 0; j < 4; ++j) v[j] = s2f(xv[j]);
    float s = v[0] + v[1] + v[2] + v[3];
    #pragma unroll
    for (int o = 1; o <= 32; o <<= 1) s += __shfl_xor(s, o);
    float mean = s * (1.f / 256.f);
    float ss = 0.f;
    #pragma unroll
    for (int j = 0; j < 4; ++j) { float d = v[j] - mean; ss += d * d; }
    #pragma unroll
    for (int o = 1; o <= 32; o <<= 1) ss += __shfl_xor(ss, o);
    float inv = rsqrtf(ss * (1.f / 256.f) + 1e-5f);
    bf16x4 wv = *(const bf16x4*)&nw[lane * 4];
    bf16x4 bv = *(const bf16x4*)&nb[lane * 4];
    bf16 ov[4];
    #pragma unroll
    for (int j = 0; j < 4; ++j) {
        float y = (v[j] - mean) * inv * s2f(wv[j]) + s2f(bv[j]);
        ov[j] = f2b(0.5f * y * (1.f + erff(y * 0.70710678118654752f)));
    }
    *(bf16x4*)&xout[(size_t)r * 256 + lane * 4] = *(bf16x4*)ov;
}

// ---------------------------------------------------------------------------
// Branch-1 attention, split-key flash (r7-verified structure). Sweep 2 now
// reads K fragments directly from global (L2-hot) -> no restaging/barriers.
// ---------------------------------------------------------------------------
__global__ __launch_bounds__(512) void attn1_split(
    const bf16* __restrict__ q1, const bf16* __restrict__ k1,
    const bf16* __restrict__ v1T, bf16* __restrict__ attn_out, float* __restrict__ g)
{
    __shared__ bf16 Kt[2][64][40];      // per-group K tile (key-major)
    __shared__ bf16 Vt[2][32][68];      // per-group V^T tile (ch-major)
    __shared__ bf16 PTT[8][16][72];     // per-wave P^T strip [q][k]
    __shared__ float gp[1024];
    __shared__ float Lcmb[4][16];       // group-1 partial l
    __shared__ float rls[4][16];        // final 1/l per (qg, q)
    __shared__ __align__(16) float Ocmb[4][16][36]; // group-1 partial O^T

    int t = threadIdx.x;
    int blk = blockIdx.x;
    int qc = blk & 63, h = (blk >> 6) & 3, b = blk >> 8;
    int n0 = qc * 64;
    int w = t >> 6, l = t & 63, lane16 = l & 15, quad = l >> 4;
    int grp = w >> 2, qg = w & 3;
    int tg = t & 255;                    // group-local thread id
    const float scale = 0.17677669529663687f;   // 1/sqrt(32)

    const bf16* Kbase = k1 + (size_t)b * 1024 * 128 + 32 * h + (size_t)(grp * 512) * 128;
    const bf16* Vbase = v1T + (size_t)((b * 4 + h) * 32) * 1024 + grp * 512;
    bf16x8 qa = *(const bf16x8*)&q1[(size_t)(b * 4096 + n0 + 16 * qg + lane16) * 128 + 32 * h + quad * 8];

    for (int i = t; i < 1024; i += 512) gp[i] = 0.f;

    int sr = tg >> 2, sc = (tg & 3) * 8;        // K staging: 64 rows x 32
    int vrow = tg >> 3, vcol = (tg & 7) * 8;    // V staging: 32 rows x 64
    bf16* ptt = &PTT[w][0][0];

    float lacc = 0.f;
    f32x4 oT0 = {}, oT1 = {};

    // ---- sweep 1 over this group's 8 key tiles ----
    for (int ktl = 0; ktl < 8; ++ktl) {
        *(bf16x8*)&Kt[grp][sr][sc] = *(const bf16x8*)&Kbase[(size_t)(ktl * 64 + sr) * 128 + sc];
        *(bf16x8*)&Vt[grp][vrow][vcol] = *(const bf16x8*)&Vbase[(size_t)vrow * 1024 + ktl * 64 + vcol];
        __syncthreads();
        #pragma unroll
        for (int st = 0; st < 4; ++st) {
            bf16x8 kf = *(const bf16x8*)&Kt[grp][st * 16 + lane16][quad * 8];
            f32x4 z = {0.f, 0.f, 0.f, 0.f};
            f32x4 sT = __builtin_amdgcn_mfma_f32_16x16x32_bf16(kf, qa, z, 0, 0, 0);
            bf16 pk[4];
            #pragma unroll
            for (int r = 0; r < 4; ++r) {
                float p = __expf(sT[r] * scale);
                lacc += p;
                pk[r] = f2b(p);
            }
            *(bf16x4*)&ptt[lane16 * 72 + st * 16 + quad * 4] = *(bf16x4*)pk;
        }
        #pragma unroll
        for (int kh = 0; kh < 2; ++kh) {
            bf16x8 pf = *(const bf16x8*)&ptt[lane16 * 72 + kh * 32 + quad * 8];
            bf16x8 vf0 = *(const bf16x8*)&Vt[grp][lane16][kh * 32 + quad * 8];
            bf16x8 vf1 = *(const bf16x8*)&Vt[grp][16 + lane16][kh * 32 + quad * 8];
            oT0 = __builtin_amdgcn_mfma_f32_16x16x32_bf16(vf0, pf, oT0, 0, 0, 0);
            oT1 = __builtin_amdgcn_mfma_f32_16x16x32_bf16(vf1, pf, oT1, 0, 0, 0);
        }
        __syncthreads();
    }

    // partial l for q = lane16 (sum over quads)
    lacc += __shfl_xor(lacc, 16);
    lacc += __shfl_xor(lacc, 32);

    // ---- combine halves ----
    if (grp == 1) {
        if (quad == 0) Lcmb[qg][lane16] = lacc;
        *(f32x4*)&Ocmb[qg][lane16][quad * 4]      = oT0;
        *(f32x4*)&Ocmb[qg][lane16][16 + quad * 4] = oT1;
    }
    __syncthreads();
    if (grp == 0) {
        float ltot = lacc + Lcmb[qg][lane16];
        float rl = 1.f / ltot;
        if (quad == 0) rls[qg][lane16] = rl;
        f32x4 p0 = *(const f32x4*)&Ocmb[qg][lane16][quad * 4];
        f32x4 p1 = *(const f32x4*)&Ocmb[qg][lane16][16 + quad * 4];
        bf16 ov0[4], ov1[4];
        #pragma unroll
        for (int r = 0; r < 4; ++r) {
            ov0[r] = f2b((oT0[r] + p0[r]) * rl);
            ov1[r] = f2b((oT1[r] + p1[r]) * rl);
        }
        size_t ro = (size_t)(b * 4096 + n0 + 16 * qg + lane16) * 256 + 32 * h;
        *(bf16x4*)&attn_out[ro + quad * 4]      = *(bf16x4*)ov0;
        *(bf16x4*)&attn_out[ro + 16 + quad * 4] = *(bf16x4*)ov1;
    }
    __syncthreads();

    float rlq[4];
    #pragma unroll
    for (int r = 0; r < 4; ++r) rlq[r] = rls[qg][quad * 4 + r];

    // ---- sweep 2: g column sums (normalized); K direct from global (L2) ----
    for (int ktl = 0; ktl < 8; ++ktl) {
        #pragma unroll
        for (int st = 0; st < 4; ++st) {
            bf16x8 kf = *(const bf16x8*)&Kbase[(size_t)(ktl * 64 + st * 16 + lane16) * 128 + quad * 8];
            f32x4 z = {0.f, 0.f, 0.f, 0.f};
            f32x4 s = __builtin_amdgcn_mfma_f32_16x16x32_bf16(qa, kf, z, 0, 0, 0);
            float cs = 0.f;
            #pragma unroll
            for (int r = 0; r < 4; ++r) cs += __expf(s[r] * scale) * rlq[r];
            cs += __shfl_xor(cs, 16);
            cs += __shfl_xor(cs, 32);
            if (quad == 0) atomicAdd(&gp[grp * 512 + ktl * 64 + st * 16 + lane16], cs);
        }
    }
    __syncthreads();

    for (int i = t; i < 1024; i += 512)
        atomicAdd(&g[(b << 10) + i], gp[i] * (1.f / 16384.f));
}

// ---------------------------------------------------------------------------
// Branch-2 windowed attention via MFMA: one wave per (window, head).
// Block 256 = 4 heads of one (b, window); grid 1024 = b*win.
// S^T = mfma32(Kfrag, Qfrag) -> C[key=quad*4+r][q=lane16]; softmax in-reg;
// normalized P -> wave-private LDS strip (q-major, K=32 zero-padded);
// O = mfma32(V^T frag, P frag) -> C[ch=quad*4+r][q=lane16].
// ---------------------------------------------------------------------------
__global__ __launch_bounds__(256) void attn2_mfma(
    const bf16* __restrict__ q2, const bf16* __restrict__ kv2,
    bf16* __restrict__ attn_out, float* __restrict__ lm)
{
    __shared__ bf16 PT2[4][16 * 40];   // per-wave P strip [q][k], k 16..31 zero
    __shared__ float lmw[16];
    int t = threadIdx.x;
    int blk = blockIdx.x;
    int b = blk >> 8, win = blk & 255;
    int wi = win >> 4, wj = win & 15;
    int h = t >> 6, l = t & 63, lane16 = l & 15, quad = l >> 4;
    const float scale = 0.17677669529663687f;

    if (t < 16) lmw[t] = 0.f;
    bf16* ptt = &PT2[h][0];
    {   // zero pad columns 16..31 of own strip (wave-private)
        bf16 zz[4] = {};
        *(bf16x4*)&ptt[lane16 * 40 + 16 + quad * 4] = *(bf16x4*)zz;
    }
    __syncthreads();

    size_t base = (size_t)(b * 4096);
    int r0 = wi * 4, c0w = wj * 4;
    // token for window-local index idx (0..15)
    int tq = (r0 + (lane16 >> 2)) * 64 + c0w + (lane16 & 3);

    bf16x8 qa = *(const bf16x8*)&q2[(base + tq) * 128 + h * 32 + quad * 8];
    bf16x8 kf = *(const bf16x8*)&kv2[(base + tq) * 256 + h * 32 + quad * 8];

    f32x4 z = {0.f, 0.f, 0.f, 0.f};
    f32x4 sT = __builtin_amdgcn_mfma_f32_16x16x32_bf16(kf, qa, z, 0, 0, 0);
    // sT[key=quad*4+r][q=lane16]
    float sv[4];
    #pragma unroll
    for (int r = 0; r < 4; ++r) sv[r] = sT[r] * scale;
    float mx = fmaxf(fmaxf(sv[0], sv[1]), fmaxf(sv[2], sv[3]));
    mx = fmaxf(mx, __shfl_xor(mx, 16));
    mx = fmaxf(mx, __shfl_xor(mx, 32));
    float p[4], lsum = 0.f;
    #pragma unroll
    for (int r = 0; r < 4; ++r) { p[r] = __expf(sv[r] - mx); lsum += p[r]; }
    lsum += __shfl_xor(lsum, 16);
    lsum += __shfl_xor(lsum, 32);
    float rl = 1.f / lsum;
    bf16 pk[4];
    #pragma unroll
    for (int r = 0; r < 4; ++r) { p[r] *= rl; pk[r] = f2b(p[r]); }
    *(bf16x4*)&ptt[lane16 * 40 + quad * 4] = *(bf16x4*)pk;

    // V^T A-frags: A[ch=lane16(+16)][key=quad*8+j]; keys >= 16 are zero pad
    bf16x8 vf0 = {}, vf1 = {};
    if (quad < 2) {
        #pragma unroll
        for (int jj = 0; jj < 8; ++jj) {
            int key = quad * 8 + jj;
            int tk = (r0 + (key >> 2)) * 64 + c0w + (key & 3);
            const short* vp = (const short*)&kv2[(base + tk) * 256 + 128 + h * 32];
            vf0[jj] = vp[lane16];
            vf1[jj] = vp[16 + lane16];
        }
    }
    bf16x8 pf = *(const bf16x8*)&ptt[lane16 * 40 + quad * 8];
    f32x4 o0 = __builtin_amdgcn_mfma_f32_16x16x32_bf16(vf0, pf, z, 0, 0, 0);
    f32x4 o1 = __builtin_amdgcn_mfma_f32_16x16x32_bf16(vf1, pf, z, 0, 0, 0);
    // o[ch=quad*4+r][q=lane16]
    {
        bf16 ov0[4], ov1[4];
        #pragma unroll
        for (int r = 0; r < 4; ++r) { ov0[r] = f2b(o0[r]); ov1[r] = f2b(o1[r]); }
        bf16* op = attn_out + (base + tq) * 256 + 128 + h * 32;
        *(bf16x4*)&op[quad * 4]      = *(bf16x4*)ov0;
        *(bf16x4*)&op[16 + quad * 4] = *(bf16x4*)ov1;
    }

    // lm: colsum over q (lanes16) of normalized p, then over heads via LDS
    #pragma unroll
    for (int r = 0; r < 4; ++r) {
        float c = p[r];
        c += __shfl_xor(c, 1);
        c += __shfl_xor(c, 2);
        c += __shfl_xor(c, 4);
        c += __shfl_xor(c, 8);
        if (lane16 == 0) atomicAdd(&lmw[quad * 4 + r], c);
    }
    __syncthreads();
    if (t < 16) {
        int nk = (r0 + (t >> 2)) * 64 + c0w + (t & 3);
        lm[(b << 12) + nk] = lmw[t] * (1.f / 64.f);
    }
}

// ---------------------------------------------------------------------------
__global__ void mask_combine(const float* __restrict__ lm, const float* __restrict__ g,
                             void* __restrict__ dout, const int* __restrict__ flag)
{
    int tid = blockIdx.x * 256 + threadIdx.x;   // 16384
    int b = tid >> 12, n = tid & 4095;
    int i = n >> 6, j = n & 63;
    float v = lm[tid] + g[(b << 10) + (i >> 1) * 32 + (j >> 1)];
    size_t o1 = (size_t)4194304 + (b << 12) + i * 64 + j;
    size_t o2 = (size_t)4194304 + 16384 + (b << 12) + j * 64 + i;
    if (*flag) { ((float*)dout)[o1] = v; ((float*)dout)[o2] = v; }
    else       { ((bf16*)dout)[o1] = f2b(v); ((bf16*)dout)[o2] = f2b(v); }
}

// ---------------------------------------------------------------------------
extern "C" void kernel_launch(void* const* d_in, const int* in_sizes, int n_in,
                              void* d_out, int out_size, void* d_ws, size_t ws_size,
                              hipStream_t stream)
{
    char* ws = (char*)d_ws;
    size_t off = 0;
    auto alloc = [&](size_t bytes) {
        void* p = ws + off;
        off += (bytes + 255) & ~(size_t)255;
        return p;
    };
    bf16* cx       = (bf16*)alloc((size_t)4194304 * 2);
    bf16* lepe_lin = (bf16*)alloc((size_t)4194304 * 2);   // reused as attn_out
    bf16* attn_out = lepe_lin;
    bf16* lepe     = (bf16*)alloc((size_t)4194304 * 2);
    bf16* q1buf    = (bf16*)alloc((size_t)2097152 * 2);
    bf16* q2buf    = (bf16*)alloc((size_t)2097152 * 2);
    bf16* kv2buf   = (bf16*)alloc((size_t)4194304 * 2);
    bf16* xs_pre   = (bf16*)alloc((size_t)1048576 * 2);   // later reused: k1 + v1T
    bf16* k1buf    = xs_pre;                               // 524288 elems
    bf16* v1Tbuf   = xs_pre + 524288;                      // 524288 elems
    bf16* xs       = (bf16*)alloc((size_t)1048576 * 2);
    bf16* wTqkv    = (bf16*)alloc((size_t)196608 * 2);     // 768 x 256
    bf16* kv1_wT   = (bf16*)alloc(65536 * 2);
    bf16* proj_wT  = (bf16*)alloc(65536 * 2);
    bf16* sr_wT    = (bf16*)alloc(262144 * 2);
    bf16* dwT      = (bf16*)alloc(2304 * 2);
    bf16* bcat     = (bf16*)alloc(768 * 2);
    bf16* ckv1b    = (bf16*)alloc(256 * 2);
    bf16* csrb     = (bf16*)alloc(256 * 2);
    bf16* cnw      = (bf16*)alloc(256 * 2);
    bf16* cnb      = (bf16*)alloc(256 * 2);
    bf16* cpb      = (bf16*)alloc(256 * 2);
    bf16* clcb     = (bf16*)alloc(256 * 2);
    float* gbuf    = (float*)alloc(4096 * 4);
    float* lmbuf   = (float*)alloc(16384 * 4);
    int*   flag    = (int*)alloc(256);

    detect_dtype<<<1, 256, 0, stream>>>(d_in[0], flag);

    convert_x4<<<4096, 256, 0, stream>>>(d_in[0], cx, flag);

    MiscArgs ma;
    ma.srw = d_in[13]; ma.srwT = sr_wT;
    ma.dww = d_in[11]; ma.dwT = dwT;
    ma.psrc[0] = d_in[10]; ma.pdst[0] = bcat;       ma.pn[0] = 256;  // lepe_b
    ma.psrc[1] = d_in[2];  ma.pdst[1] = bcat + 256; ma.pn[1] = 128;  // q1_b
    ma.psrc[2] = d_in[6];  ma.pdst[2] = bcat + 384; ma.pn[2] = 128;  // q2_b
    ma.psrc[3] = d_in[8];  ma.pdst[3] = bcat + 512; ma.pn[3] = 256;  // kv2_b
    ma.psrc[4] = d_in[4];  ma.pdst[4] = ckv1b;      ma.pn[4] = 256;
    ma.psrc[5] = d_in[14]; ma.pdst[5] = csrb;       ma.pn[5] = 256;
    ma.psrc[6] = d_in[15]; ma.pdst[6] = cnw;        ma.pn[6] = 256;
    ma.psrc[7] = d_in[16]; ma.pdst[7] = cnb;        ma.pn[7] = 256;
    ma.psrc[8] = d_in[18]; ma.pdst[8] = cpb;        ma.pn[8] = 256;
    ma.psrc[9] = d_in[12]; ma.pdst[9] = clcb;       ma.pn[9] = 256;
    convert_misc<<<1043, 256, 0, stream>>>(ma, flag);

    WTArgs wa;
    wa.src[0] = d_in[9];  wa.dst[0] = wTqkv;             wa.N[0] = 256;
    wa.src[1] = d_in[1];  wa.dst[1] = wTqkv + 256 * 256; wa.N[1] = 128;
    wa.src[2] = d_in[5];  wa.dst[2] = wTqkv + 384 * 256; wa.N[2] = 128;
    wa.src[3] = d_in[7];  wa.dst[3] = wTqkv + 512 * 256; wa.N[3] = 256;
    wa.src[4] = d_in[3];  wa.dst[4] = kv1_wT;            wa.N[4] = 256;
    wa.src[5] = d_in[17]; wa.dst[5] = proj_wT;           wa.N[5] = 256;
    int bo[7] = {0, 256, 384, 512, 768, 1024, 1280};
    for (int i = 0; i < 7; ++i) wa.blkoff[i] = bo[i];
    convert_wT_multi<<<1280, 256, 0, stream>>>(wa, flag);

    hipMemsetAsync(gbuf, 0, 4096 * 4, stream);

    // fused x-projections (128x128 tile)
    gemm_qkv128<<<dim3(128, 6), 256, 0, stream>>>(cx, wTqkv, bcat, lepe_lin, q1buf, q2buf, kv2buf);
    // spatial reduction branch
    gemm_sr_mfma<<<dim3(64, 4), 256, 0, stream>>>(cx, sr_wT, csrb, xs_pre);
    ln_gelu_w<<<1024, 256, 0, stream>>>(xs_pre, cnw, cnb, xs);
    gemm_kv1<<<dim3(64, 4), 256, 0, stream>>>(xs, kv1_wT, ckv1b, k1buf, v1Tbuf);
    // lepe (consumes lepe_lin; must precede attn kernels which reuse that slot)
    dwconv3p<<<1024, 256, 0, stream>>>(lepe_lin, dwT, clcb, lepe);
    // attentions
    attn1_split<<<1024, 512, 0, stream>>>(q1buf, k1buf, v1Tbuf, attn_out, gbuf);
    attn2_mfma<<<1024, 256, 0, stream>>>(q2buf, kv2buf, attn_out, lmbuf);
    // projection epilogue (128x128 tile)
    gemm_proj128<<<dim3(128, 2), 256, 0, stream>>>(attn_out, lepe, proj_wT, cpb, d_out, flag);
    // masks
    mask_combine<<<64, 256, 0, stream>>>(lmbuf, gbuf, d_out, flag);
}